// Round 1
// baseline (60257.489 us; speedup 1.0000x reference)
//
#include <hip/hip_runtime.h>

typedef __attribute__((ext_vector_type(8))) short short8;
typedef __attribute__((ext_vector_type(4))) float f32x4;
typedef unsigned short ushort_t;

#define T_STEPS 1024
#define NWG 32

// Layer geometry:
// L0: K=820 Kpad=832 KB=26 NT=20 H=308 hoff=0
// L1: K=512 Kpad=512 KB=16 NT=13 H=204 hoff=308
// L2: K=716 Kpad=736 KB=23 NT=32 H=512 hoff=512

// packed-weight bases (elements)
#define PACK0 0
#define PACK1 1064960
#define PACK2 1490944

// ws offsets (bytes)
#define WS_BAR   0
#define WS_MU    4096
#define WS_RSTD  266240
#define WS_HI    530432
#define WS_HC    688128
#define WS_HM    792576
#define WS_PACK  1054720

__device__ __forceinline__ ushort_t f2bf(float f) {
  union { float f; unsigned u; } un; un.f = f;
  unsigned r = (un.u + 0x7fffu + ((un.u >> 16) & 1u)) >> 16;
  return (ushort_t)r;
}

__device__ __forceinline__ void gbar(unsigned* ctr, unsigned target) {
  __syncthreads();
  if (threadIdx.x == 0) {
    __hip_atomic_fetch_add(ctr, 1u, __ATOMIC_RELEASE, __HIP_MEMORY_SCOPE_AGENT);
    while (__hip_atomic_load(ctr, __ATOMIC_RELAXED, __HIP_MEMORY_SCOPE_AGENT) < target)
      __builtin_amdgcn_s_sleep(1);
    __threadfence();  // acquire: make other wgs' writes visible
  }
  __syncthreads();
}

// ---------------- LayerNorm stats: one wave per (b,t) row ----------------
__global__ __launch_bounds__(256) void ln_stats(const float* __restrict__ x,
                                                float* __restrict__ mu,
                                                float* __restrict__ rstd) {
  const int row = blockIdx.x * 4 + (threadIdx.x >> 6);
  const int lane = threadIdx.x & 63;
  const float* xr = x + (size_t)row * 512;
  float4 v0 = *(const float4*)(xr + lane * 8);
  float4 v1 = *(const float4*)(xr + lane * 8 + 4);
  float s = v0.x + v0.y + v0.z + v0.w + v1.x + v1.y + v1.z + v1.w;
  float q = v0.x*v0.x + v0.y*v0.y + v0.z*v0.z + v0.w*v0.w
          + v1.x*v1.x + v1.y*v1.y + v1.z*v1.z + v1.w*v1.w;
  for (int m = 1; m <= 32; m <<= 1) {
    s += __shfl_xor(s, m, 64);
    q += __shfl_xor(q, m, 64);
  }
  if (lane == 0) {
    float mean = s * (1.f / 512.f);
    float var = q * (1.f / 512.f) - mean * mean;
    mu[row] = mean;
    rstd[row] = rsqrtf(var + 1e-5f);
  }
}

// ---------------- init hidden state from h0 ----------------
__global__ void init_h(const float* __restrict__ h0, float* hi, float* hc, float* hm) {
  int i = blockIdx.x * 256 + threadIdx.x;
  if (i >= 64 * 1024) return;
  int b = i >> 10, c = i & 1023;
  float v = h0[i];
  if (c < 308) hi[b * 308 + c] = v;
  else if (c < 512) hc[b * 204 + (c - 308)] = v;
  else hm[b * 512 + (c - 512)] = v;
}

// ---------------- pack masked weights to bf16 MFMA B-frag order ----------------
struct PackP {
  const float* w[12];
  const float* msk[3];
  ushort_t* pack;
};

__global__ __launch_bounds__(256) void ncp_pack(PackP P) {
  int u = blockIdx.x * 256 + threadIdx.x;
  int layer, rem, KB, K, H;
  size_t base;
  if (u < 133120)      { layer = 0; rem = u;          KB = 26; K = 820; H = 308; base = PACK0; }
  else if (u < 186368) { layer = 1; rem = u - 133120; KB = 16; K = 512; H = 204; base = PACK1; }
  else if (u < 374784) { layer = 2; rem = u - 186368; KB = 23; K = 716; H = 512; base = PACK2; }
  else return;
  const int lane = rem & 63;
  const int mat = (rem >> 6) & 3;
  const int kb = (rem >> 8) % KB;
  const int nt = (rem >> 8) / KB;
  const float* W = P.w[layer * 4 + mat];
  const float* M = (mat < 2) ? P.msk[layer] : nullptr;
  const int n = nt * 16 + (lane & 15);
  const int kbase = kb * 32 + ((lane >> 4) << 3);
  ushort_t* dst = P.pack + base + (size_t)rem * 8;
#pragma unroll
  for (int j = 0; j < 8; ++j) {
    int k = kbase + j;
    float v = 0.f;
    if (n < H && k < K) {
      v = W[(size_t)n * K + k];
      if (M) v *= M[(size_t)n * K + k];
    }
    dst[j] = f2bf(v);
  }
}

// ---------------- main persistent kernel ----------------
struct MainP {
  const float* x;
  const float* gamma;
  const float* beta;
  const float* bias[12];
  const float* mu;
  const float* rstd;
  float* hi;
  float* hc;
  float* hm;
  const ushort_t* pack;
  unsigned* bar;
  float* y;
  float* hfin;
};

__device__ __forceinline__ void tile_task(
    const ushort_t* __restrict__ packL, const ushort_t* __restrict__ Alds,
    int KB, int nt, int H, int lane, int mtile, int t, bool last,
    const float* __restrict__ bp1, const float* __restrict__ bp2,
    const float* __restrict__ bpa, const float* __restrict__ bpb,
    float* __restrict__ hout, float* __restrict__ y,
    float* __restrict__ hfin, int hoff)
{
  f32x4 a0 = {0.f, 0.f, 0.f, 0.f}, a1 = a0, a2 = a0, a3 = a0;
  const ushort_t* bp = packL + (size_t)nt * KB * 2048;
  for (int kb = 0; kb < KB; ++kb) {
    short8 av = *(const short8*)(Alds + (kb * 64 + lane) * 8);
    const ushort_t* bb = bp + kb * 2048 + lane * 8;
    short8 b0 = *(const short8*)(bb);
    short8 b1 = *(const short8*)(bb + 512);
    short8 b2 = *(const short8*)(bb + 1024);
    short8 b3 = *(const short8*)(bb + 1536);
    a0 = __builtin_amdgcn_mfma_f32_16x16x32_bf16(av, b0, a0, 0, 0, 0);
    a1 = __builtin_amdgcn_mfma_f32_16x16x32_bf16(av, b1, a1, 0, 0, 0);
    a2 = __builtin_amdgcn_mfma_f32_16x16x32_bf16(av, b2, a2, 0, 0, 0);
    a3 = __builtin_amdgcn_mfma_f32_16x16x32_bf16(av, b3, a3, 0, 0, 0);
  }
  const int n = nt * 16 + (lane & 15);
  if (n < H) {
    float c1 = bp1[n], c2 = bp2[n], ca = bpa[n], cb = bpb[n];
    const int r0 = (lane >> 4) << 2;
#pragma unroll
    for (int j = 0; j < 4; ++j) {
      int brow = mtile * 16 + r0 + j;
      float s = 1.f / (1.f + __expf(-(a2[j] + ca + a3[j] + cb)));
      float f1 = 1.f - 2.f / (1.f + __expf(2.f * (a0[j] + c1)));
      float f2 = 1.f - 2.f / (1.f + __expf(2.f * (a1[j] + c2)));
      float v = f1 * (1.f - s) + s * f2;
      hout[brow * H + n] = v;
      if (y) y[((size_t)brow * T_STEPS + t) * 512 + n] = v;
      if (last) hfin[brow * 1024 + hoff + n] = v;
    }
  }
}

__global__ __launch_bounds__(256) void ncp_main(MainP P) {
  const int tid = threadIdx.x;
  const int lane = tid & 63;
  const int wv = tid >> 6;
  const int wg = blockIdx.x;
  const int mtile = wg & 3;
  const int ntask = (wg >> 2) * 4 + wv;  // 0..31 unique per mtile

  __shared__ __align__(16) ushort_t Alds[26 * 64 * 8];

  unsigned rnd = 0;
  for (int t = 0; t < T_STEPS; ++t) {
    const int cur = t & 1, nxt = cur ^ 1;
    const float* hi_c = P.hi + cur * (64 * 308);
    float*       hi_n = P.hi + nxt * (64 * 308);
    const float* hc_c = P.hc + cur * (64 * 204);
    float*       hc_n = P.hc + nxt * (64 * 204);
    const float* hm_c = P.hm + cur * (64 * 512);
    float*       hm_n = P.hm + nxt * (64 * 512);
    const bool last = (t == T_STEPS - 1);

    // ---- LAYER 0: z = [LN(x_t) | h_i] ----
    for (int p = tid; p < 26 * 64; p += 256) {
      const int kb = p >> 6, ln = p & 63;
      const int brow = mtile * 16 + (ln & 15);
      const int kbase = kb * 32 + ((ln >> 4) << 3);
      const float muv = P.mu[brow * T_STEPS + t];
      const float rsv = P.rstd[brow * T_STEPS + t];
      const float* xrow = P.x + ((size_t)brow * T_STEPS + t) * 512;
      ushort_t* dst = Alds + p * 8;
#pragma unroll
      for (int j = 0; j < 8; ++j) {
        const int k = kbase + j;
        float v;
        if (k < 512) v = (xrow[k] - muv) * rsv * P.gamma[k] + P.beta[k];
        else if (k < 820) v = hi_c[brow * 308 + (k - 512)];
        else v = 0.f;
        dst[j] = f2bf(v);
      }
    }
    __syncthreads();
    if (ntask < 20)
      tile_task(P.pack + PACK0, Alds, 26, ntask, 308, lane, mtile, t, last,
                P.bias[0], P.bias[1], P.bias[2], P.bias[3],
                hi_n, nullptr, P.hfin, 0);
    gbar(P.bar, (++rnd) * NWG);

    // ---- LAYER 1: z = [h_i_new | h_c] ----
    for (int p = tid; p < 16 * 64; p += 256) {
      const int kb = p >> 6, ln = p & 63;
      const int brow = mtile * 16 + (ln & 15);
      const int kbase = kb * 32 + ((ln >> 4) << 3);
      ushort_t* dst = Alds + p * 8;
#pragma unroll
      for (int j = 0; j < 8; ++j) {
        const int k = kbase + j;
        float v = (k < 308) ? hi_n[brow * 308 + k] : hc_c[brow * 204 + (k - 308)];
        dst[j] = f2bf(v);
      }
    }
    __syncthreads();
    if (ntask < 13)
      tile_task(P.pack + PACK1, Alds, 16, ntask, 204, lane, mtile, t, last,
                P.bias[4], P.bias[5], P.bias[6], P.bias[7],
                hc_n, nullptr, P.hfin, 308);
    gbar(P.bar, (++rnd) * NWG);

    // ---- LAYER 2: z = [h_c_new | h_m] ----
    for (int p = tid; p < 23 * 64; p += 256) {
      const int kb = p >> 6, ln = p & 63;
      const int brow = mtile * 16 + (ln & 15);
      const int kbase = kb * 32 + ((ln >> 4) << 3);
      ushort_t* dst = Alds + p * 8;
#pragma unroll
      for (int j = 0; j < 8; ++j) {
        const int k = kbase + j;
        float v;
        if (k < 204) v = hc_n[brow * 204 + k];
        else if (k < 716) v = hm_c[brow * 512 + (k - 204)];
        else v = 0.f;
        dst[j] = f2bf(v);
      }
    }
    __syncthreads();
    tile_task(P.pack + PACK2, Alds, 23, ntask, 512, lane, mtile, t, last,
              P.bias[8], P.bias[9], P.bias[10], P.bias[11],
              hm_n, P.y, P.hfin, 512);
    // L2 output is only read after the next step's two gbars -> local sync suffices
    __syncthreads();
  }
}

extern "C" void kernel_launch(void* const* d_in, const int* in_sizes, int n_in,
                              void* d_out, int out_size, void* d_ws, size_t ws_size,
                              hipStream_t stream) {
  const float* x     = (const float*)d_in[27];
  const float* h0    = (const float*)d_in[28];
  const float* gamma = (const float*)d_in[29];
  const float* beta  = (const float*)d_in[30];

  char* ws = (char*)d_ws;
  unsigned* bar = (unsigned*)(ws + WS_BAR);
  float* mu   = (float*)(ws + WS_MU);
  float* rstd = (float*)(ws + WS_RSTD);
  float* hi   = (float*)(ws + WS_HI);
  float* hc   = (float*)(ws + WS_HC);
  float* hm   = (float*)(ws + WS_HM);
  ushort_t* pack = (ushort_t*)(ws + WS_PACK);

  float* y = (float*)d_out;
  float* hfin = y + (size_t)64 * 1024 * 512;

  hipMemsetAsync(bar, 0, 4096, stream);

  ln_stats<<<dim3(16384), dim3(256), 0, stream>>>(x, mu, rstd);
  init_h<<<dim3(256), dim3(256), 0, stream>>>(h0, hi, hc, hm);

  PackP pp;
  for (int l = 0; l < 3; ++l) {
    for (int m = 0; m < 4; ++m) pp.w[l * 4 + m] = (const float*)d_in[l * 9 + 2 * m];
    pp.msk[l] = (const float*)d_in[l * 9 + 8];
  }
  pp.pack = pack;
  ncp_pack<<<dim3(1464), dim3(256), 0, stream>>>(pp);

  MainP mp;
  mp.x = x; mp.gamma = gamma; mp.beta = beta;
  for (int l = 0; l < 3; ++l)
    for (int m = 0; m < 4; ++m) mp.bias[l * 4 + m] = (const float*)d_in[l * 9 + 2 * m + 1];
  mp.mu = mu; mp.rstd = rstd;
  mp.hi = hi; mp.hc = hc; mp.hm = hm;
  mp.pack = pack; mp.bar = bar;
  mp.y = y; mp.hfin = hfin;
  ncp_main<<<dim3(NWG), dim3(256), 0, stream>>>(mp);
}

// Round 3
// 53839.514 us; speedup vs baseline: 1.1192x; 1.1192x over previous
//
#include <hip/hip_runtime.h>

typedef __attribute__((ext_vector_type(8))) short short8;
typedef __attribute__((ext_vector_type(4))) float f32x4;
typedef unsigned short ushort_t;

#define T_STEPS 1024
#define NWG 32

// Layer geometry:
// L0: K=820 Kpad=832 KB=26 NT=20 H=308 hoff=0
// L1: K=512 Kpad=512 KB=16 NT=13 H=204 hoff=308
// L2: K=716 Kpad=736 KB=23 NT=32 H=512 hoff=512

// packed-weight bases (elements)
#define PACK0 0
#define PACK1 1064960
#define PACK2 1490944

// ws offsets (bytes)
#define WS_BAR   0
#define WS_MU    4096
#define WS_RSTD  266240
#define WS_HI    530432
#define WS_HC    688128
#define WS_HM    792576
#define WS_PACK  1054720

__device__ __forceinline__ ushort_t f2bf(float f) {
  union { float f; unsigned u; } un; un.f = f;
  unsigned r = (un.u + 0x7fffu + ((un.u >> 16) & 1u)) >> 16;
  return (ushort_t)r;
}

// h-state exchange: relaxed system-scope ops -> global_load/store_dword sc0 sc1
// (bypass L1+L2 both sides; no cache-maintenance instructions anywhere).
__device__ __forceinline__ void st_coh(float* p, float v) {
  __hip_atomic_store(p, v, __ATOMIC_RELAXED, __HIP_MEMORY_SCOPE_SYSTEM);
}
__device__ __forceinline__ float ld_coh(const float* p) {
  return __hip_atomic_load((const float*)p, __ATOMIC_RELAXED, __HIP_MEMORY_SCOPE_SYSTEM);
}

// Relaxed global barrier: per-wave store drain + relaxed counter. No release/
// acquire fences -> no buffer_wbl2/buffer_inv -> packed weights stay in L2.
__device__ __forceinline__ void gbar(unsigned* ctr, unsigned target) {
  asm volatile("s_waitcnt vmcnt(0)" ::: "memory");
  __syncthreads();
  if (threadIdx.x == 0) {
    __hip_atomic_fetch_add(ctr, 1u, __ATOMIC_RELAXED, __HIP_MEMORY_SCOPE_SYSTEM);
    while (__hip_atomic_load(ctr, __ATOMIC_RELAXED, __HIP_MEMORY_SCOPE_SYSTEM) < target)
      __builtin_amdgcn_s_sleep(1);
  }
  __syncthreads();
}

// ---------------- LayerNorm stats: one wave per (b,t) row ----------------
__global__ __launch_bounds__(256) void ln_stats(const float* __restrict__ x,
                                                float* __restrict__ mu,
                                                float* __restrict__ rstd) {
  const int row = blockIdx.x * 4 + (threadIdx.x >> 6);
  const int lane = threadIdx.x & 63;
  const float* xr = x + (size_t)row * 512;
  float4 v0 = *(const float4*)(xr + lane * 8);
  float4 v1 = *(const float4*)(xr + lane * 8 + 4);
  float s = v0.x + v0.y + v0.z + v0.w + v1.x + v1.y + v1.z + v1.w;
  float q = v0.x*v0.x + v0.y*v0.y + v0.z*v0.z + v0.w*v0.w
          + v1.x*v1.x + v1.y*v1.y + v1.z*v1.z + v1.w*v1.w;
  for (int m = 1; m <= 32; m <<= 1) {
    s += __shfl_xor(s, m, 64);
    q += __shfl_xor(q, m, 64);
  }
  if (lane == 0) {
    float mean = s * (1.f / 512.f);
    float var = q * (1.f / 512.f) - mean * mean;
    mu[row] = mean;
    rstd[row] = rsqrtf(var + 1e-5f);
  }
}

// ---------------- init hidden state from h0 ----------------
__global__ void init_h(const float* __restrict__ h0, float* hi, float* hc, float* hm) {
  int i = blockIdx.x * 256 + threadIdx.x;
  if (i >= 64 * 1024) return;
  int b = i >> 10, c = i & 1023;
  float v = h0[i];
  if (c < 308) hi[b * 308 + c] = v;
  else if (c < 512) hc[b * 204 + (c - 308)] = v;
  else hm[b * 512 + (c - 512)] = v;
}

// ---------------- pack masked weights to bf16 MFMA B-frag order ----------------
struct PackP {
  const float* w[12];
  const float* msk[3];
  ushort_t* pack;
};

__global__ __launch_bounds__(256) void ncp_pack(PackP P) {
  int u = blockIdx.x * 256 + threadIdx.x;
  int layer, rem, KB, K, H;
  size_t base;
  if (u < 133120)      { layer = 0; rem = u;          KB = 26; K = 820; H = 308; base = PACK0; }
  else if (u < 186368) { layer = 1; rem = u - 133120; KB = 16; K = 512; H = 204; base = PACK1; }
  else if (u < 374784) { layer = 2; rem = u - 186368; KB = 23; K = 716; H = 512; base = PACK2; }
  else return;
  const int lane = rem & 63;
  const int mat = (rem >> 6) & 3;
  const int kb = (rem >> 8) % KB;
  const int nt = (rem >> 8) / KB;
  const float* W = P.w[layer * 4 + mat];
  const float* M = (mat < 2) ? P.msk[layer] : nullptr;
  const int n = nt * 16 + (lane & 15);
  const int kbase = kb * 32 + ((lane >> 4) << 3);
  ushort_t* dst = P.pack + base + (size_t)rem * 8;
#pragma unroll
  for (int j = 0; j < 8; ++j) {
    int k = kbase + j;
    float v = 0.f;
    if (n < H && k < K) {
      v = W[(size_t)n * K + k];
      if (M) v *= M[(size_t)n * K + k];
    }
    dst[j] = f2bf(v);
  }
}

// ---------------- main persistent kernel ----------------
struct MainP {
  const float* x;
  const float* gamma;
  const float* beta;
  const float* bias[12];
  const float* mu;
  const float* rstd;
  float* hi;
  float* hc;
  float* hm;
  const ushort_t* pack;
  unsigned* bar;
  float* y;
  float* hfin;
};

__device__ __forceinline__ void tile_task(
    const ushort_t* __restrict__ packL, const ushort_t* __restrict__ Alds,
    int KB, int nt, int H, int lane, int mtile, int t, bool last,
    const float* __restrict__ bp1, const float* __restrict__ bp2,
    const float* __restrict__ bpa, const float* __restrict__ bpb,
    float* __restrict__ hout, float* __restrict__ y,
    float* __restrict__ hfin, int hoff)
{
  f32x4 a0 = {0.f, 0.f, 0.f, 0.f}, a1 = a0, a2 = a0, a3 = a0;
  const ushort_t* bp = packL + (size_t)nt * KB * 2048;
  for (int kb = 0; kb < KB; ++kb) {
    short8 av = *(const short8*)(Alds + (kb * 64 + lane) * 8);
    const ushort_t* bb = bp + kb * 2048 + lane * 8;
    short8 b0 = *(const short8*)(bb);
    short8 b1 = *(const short8*)(bb + 512);
    short8 b2 = *(const short8*)(bb + 1024);
    short8 b3 = *(const short8*)(bb + 1536);
    a0 = __builtin_amdgcn_mfma_f32_16x16x32_bf16(av, b0, a0, 0, 0, 0);
    a1 = __builtin_amdgcn_mfma_f32_16x16x32_bf16(av, b1, a1, 0, 0, 0);
    a2 = __builtin_amdgcn_mfma_f32_16x16x32_bf16(av, b2, a2, 0, 0, 0);
    a3 = __builtin_amdgcn_mfma_f32_16x16x32_bf16(av, b3, a3, 0, 0, 0);
  }
  const int n = nt * 16 + (lane & 15);
  if (n < H) {
    float c1 = bp1[n], c2 = bp2[n], ca = bpa[n], cb = bpb[n];
    const int r0 = (lane >> 4) << 2;
#pragma unroll
    for (int j = 0; j < 4; ++j) {
      int brow = mtile * 16 + r0 + j;
      float s = 1.f / (1.f + __expf(-(a2[j] + ca + a3[j] + cb)));
      float f1 = 1.f - 2.f / (1.f + __expf(2.f * (a0[j] + c1)));
      float f2 = 1.f - 2.f / (1.f + __expf(2.f * (a1[j] + c2)));
      float v = f1 * (1.f - s) + s * f2;
      st_coh(hout + brow * H + n, v);
      if (y) y[((size_t)brow * T_STEPS + t) * 512 + n] = v;
      if (last) hfin[brow * 1024 + hoff + n] = v;
    }
  }
}

__global__ __launch_bounds__(256) void ncp_main(MainP P) {
  const int tid = threadIdx.x;
  const int lane = tid & 63;
  const int wv = tid >> 6;
  const int wg = blockIdx.x;
  // mtile = wg>>3 so the 8 WGs sharing one weight tile-group land on the same
  // XCD under round-robin dispatch (perf heuristic only; any bijection is correct).
  const int mtile = wg >> 3;
  const int ntask = (wg & 7) * 4 + wv;  // 0..31 unique per mtile

  __shared__ __align__(16) ushort_t Alds[26 * 64 * 8];

  unsigned rnd = 0;
  for (int t = 0; t < T_STEPS; ++t) {
    const int cur = t & 1, nxt = cur ^ 1;
    float* hi_c = P.hi + cur * (64 * 308);
    float* hi_n = P.hi + nxt * (64 * 308);
    float* hc_c = P.hc + cur * (64 * 204);
    float* hc_n = P.hc + nxt * (64 * 204);
    float* hm_c = P.hm + cur * (64 * 512);
    float* hm_n = P.hm + nxt * (64 * 512);
    const bool last = (t == T_STEPS - 1);

    // ---- LAYER 0: z = [LN(x_t) | h_i] ----
    for (int p = tid; p < 26 * 64; p += 256) {
      const int kb = p >> 6, ln = p & 63;
      const int brow = mtile * 16 + (ln & 15);
      const int kbase = kb * 32 + ((ln >> 4) << 3);
      const float muv = P.mu[brow * T_STEPS + t];
      const float rsv = P.rstd[brow * T_STEPS + t];
      const float* xrow = P.x + ((size_t)brow * T_STEPS + t) * 512;
      ushort_t* dst = Alds + p * 8;
#pragma unroll
      for (int j = 0; j < 8; ++j) {
        const int k = kbase + j;
        float v;
        if (k < 512) v = (xrow[k] - muv) * rsv * P.gamma[k] + P.beta[k];
        else if (k < 820) v = ld_coh(hi_c + brow * 308 + (k - 512));
        else v = 0.f;
        dst[j] = f2bf(v);
      }
    }
    __syncthreads();
    if (ntask < 20)
      tile_task(P.pack + PACK0, Alds, 26, ntask, 308, lane, mtile, t, last,
                P.bias[0], P.bias[1], P.bias[2], P.bias[3],
                hi_n, nullptr, P.hfin, 0);
    gbar(P.bar, (++rnd) * NWG);

    // ---- LAYER 1: z = [h_i_new | h_c] ----
    for (int p = tid; p < 16 * 64; p += 256) {
      const int kb = p >> 6, ln = p & 63;
      const int brow = mtile * 16 + (ln & 15);
      const int kbase = kb * 32 + ((ln >> 4) << 3);
      ushort_t* dst = Alds + p * 8;
#pragma unroll
      for (int j = 0; j < 8; ++j) {
        const int k = kbase + j;
        float v = (k < 308) ? ld_coh(hi_n + brow * 308 + k)
                            : ld_coh(hc_c + brow * 204 + (k - 308));
        dst[j] = f2bf(v);
      }
    }
    __syncthreads();
    if (ntask < 13)
      tile_task(P.pack + PACK1, Alds, 16, ntask, 204, lane, mtile, t, last,
                P.bias[4], P.bias[5], P.bias[6], P.bias[7],
                hc_n, nullptr, P.hfin, 308);
    gbar(P.bar, (++rnd) * NWG);

    // ---- LAYER 2: z = [h_c_new | h_m] ----
    for (int p = tid; p < 23 * 64; p += 256) {
      const int kb = p >> 6, ln = p & 63;
      const int brow = mtile * 16 + (ln & 15);
      const int kbase = kb * 32 + ((ln >> 4) << 3);
      ushort_t* dst = Alds + p * 8;
#pragma unroll
      for (int j = 0; j < 8; ++j) {
        const int k = kbase + j;
        float v;
        if (k < 204) v = ld_coh(hc_n + brow * 204 + k);
        else if (k < 716) v = ld_coh(hm_c + brow * 512 + (k - 204));
        else v = 0.f;
        dst[j] = f2bf(v);
      }
    }
    __syncthreads();
    tile_task(P.pack + PACK2, Alds, 23, ntask, 512, lane, mtile, t, last,
              P.bias[8], P.bias[9], P.bias[10], P.bias[11],
              hm_n, P.y, P.hfin, 512);
    // hm_n consumed only after next step's two gbars (each drains vmcnt) ->
    // local sync suffices here (protects LDS reuse).
    __syncthreads();
  }
}

extern "C" void kernel_launch(void* const* d_in, const int* in_sizes, int n_in,
                              void* d_out, int out_size, void* d_ws, size_t ws_size,
                              hipStream_t stream) {
  const float* x     = (const float*)d_in[27];
  const float* h0    = (const float*)d_in[28];
  const float* gamma = (const float*)d_in[29];
  const float* beta  = (const float*)d_in[30];

  char* ws = (char*)d_ws;
  unsigned* bar = (unsigned*)(ws + WS_BAR);
  float* mu   = (float*)(ws + WS_MU);
  float* rstd = (float*)(ws + WS_RSTD);
  float* hi   = (float*)(ws + WS_HI);
  float* hc   = (float*)(ws + WS_HC);
  float* hm   = (float*)(ws + WS_HM);
  ushort_t* pack = (ushort_t*)(ws + WS_PACK);

  float* y = (float*)d_out;
  float* hfin = y + (size_t)64 * 1024 * 512;

  hipMemsetAsync(bar, 0, 4096, stream);

  ln_stats<<<dim3(16384), dim3(256), 0, stream>>>(x, mu, rstd);
  init_h<<<dim3(256), dim3(256), 0, stream>>>(h0, hi, hc, hm);

  PackP pp;
  for (int l = 0; l < 3; ++l) {
    for (int m = 0; m < 4; ++m) pp.w[l * 4 + m] = (const float*)d_in[l * 9 + 2 * m];
    pp.msk[l] = (const float*)d_in[l * 9 + 8];
  }
  pp.pack = pack;
  ncp_pack<<<dim3(1464), dim3(256), 0, stream>>>(pp);

  MainP mp;
  mp.x = x; mp.gamma = gamma; mp.beta = beta;
  for (int l = 0; l < 3; ++l)
    for (int m = 0; m < 4; ++m) mp.bias[l * 4 + m] = (const float*)d_in[l * 9 + 2 * m + 1];
  mp.mu = mu; mp.rstd = rstd;
  mp.hi = hi; mp.hc = hc; mp.hm = hm;
  mp.pack = pack; mp.bar = bar;
  mp.y = y; mp.hfin = hfin;
  ncp_main<<<dim3(NWG), dim3(256), 0, stream>>>(mp);
}

// Round 4
// 42063.367 us; speedup vs baseline: 1.4325x; 1.2800x over previous
//
#include <hip/hip_runtime.h>

typedef __attribute__((ext_vector_type(8))) short short8;
typedef __attribute__((ext_vector_type(4))) float f32x4;
typedef unsigned short ushort_t;

#define T_STEPS 1024
#define NWG 32

// Layer geometry:
// L0: K=820 Kpad=832 KB=26 NT=20 H=308 hoff=0
// L1: K=512 Kpad=512 KB=16 NT=13 H=204 hoff=308
// L2: K=716 Kpad=736 KB=23 NT=32 H=512 hoff=512

// packed-weight bases (elements)
#define PACK0 0
#define PACK1 1064960
#define PACK2 1490944

// ws offsets (bytes)
#define WS_BAR   0
#define WS_MU    4096
#define WS_RSTD  266240
#define WS_HI    530432
#define WS_HC    688128
#define WS_HM    792576
#define WS_PACK  1054720

__device__ __forceinline__ ushort_t f2bf(float f) {
  union { float f; unsigned u; } un; un.f = f;
  unsigned r = (un.u + 0x7fffu + ((un.u >> 16) & 1u)) >> 16;
  return (ushort_t)r;
}

// h-state exchange: relaxed system-scope ops -> global_load/store_dword sc0 sc1
// (bypass L1+L2 both sides; no cache-maintenance instructions anywhere).
__device__ __forceinline__ void st_coh(float* p, float v) {
  __hip_atomic_store(p, v, __ATOMIC_RELAXED, __HIP_MEMORY_SCOPE_SYSTEM);
}
__device__ __forceinline__ float ld_coh(const float* p) {
  return __hip_atomic_load((const float*)p, __ATOMIC_RELAXED, __HIP_MEMORY_SCOPE_SYSTEM);
}

// Relaxed global barrier: per-wave store drain + relaxed counter. No release/
// acquire fences -> no buffer_wbl2/buffer_inv -> packed weights stay in L2.
__device__ __forceinline__ void gbar(unsigned* ctr, unsigned target) {
  asm volatile("s_waitcnt vmcnt(0)" ::: "memory");
  __syncthreads();
  if (threadIdx.x == 0) {
    __hip_atomic_fetch_add(ctr, 1u, __ATOMIC_RELAXED, __HIP_MEMORY_SCOPE_SYSTEM);
    while (__hip_atomic_load(ctr, __ATOMIC_RELAXED, __HIP_MEMORY_SCOPE_SYSTEM) < target)
      __builtin_amdgcn_s_sleep(1);
  }
  __syncthreads();
}

// ---------------- LayerNorm stats: one wave per (b,t) row ----------------
__global__ __launch_bounds__(256) void ln_stats(const float* __restrict__ x,
                                                float* __restrict__ mu,
                                                float* __restrict__ rstd) {
  const int row = blockIdx.x * 4 + (threadIdx.x >> 6);
  const int lane = threadIdx.x & 63;
  const float* xr = x + (size_t)row * 512;
  float4 v0 = *(const float4*)(xr + lane * 8);
  float4 v1 = *(const float4*)(xr + lane * 8 + 4);
  float s = v0.x + v0.y + v0.z + v0.w + v1.x + v1.y + v1.z + v1.w;
  float q = v0.x*v0.x + v0.y*v0.y + v0.z*v0.z + v0.w*v0.w
          + v1.x*v1.x + v1.y*v1.y + v1.z*v1.z + v1.w*v1.w;
  for (int m = 1; m <= 32; m <<= 1) {
    s += __shfl_xor(s, m, 64);
    q += __shfl_xor(q, m, 64);
  }
  if (lane == 0) {
    float mean = s * (1.f / 512.f);
    float var = q * (1.f / 512.f) - mean * mean;
    mu[row] = mean;
    rstd[row] = rsqrtf(var + 1e-5f);
  }
}

// ---------------- init hidden state from h0 ----------------
__global__ void init_h(const float* __restrict__ h0, float* hi, float* hc, float* hm) {
  int i = blockIdx.x * 256 + threadIdx.x;
  if (i >= 64 * 1024) return;
  int b = i >> 10, c = i & 1023;
  float v = h0[i];
  if (c < 308) hi[b * 308 + c] = v;
  else if (c < 512) hc[b * 204 + (c - 308)] = v;
  else hm[b * 512 + (c - 512)] = v;
}

// ---------------- pack masked weights to bf16 MFMA B-frag order ----------------
struct PackP {
  const float* w[12];
  const float* msk[3];
  ushort_t* pack;
};

__global__ __launch_bounds__(256) void ncp_pack(PackP P) {
  int u = blockIdx.x * 256 + threadIdx.x;
  int layer, rem, KB, K, H;
  size_t base;
  if (u < 133120)      { layer = 0; rem = u;          KB = 26; K = 820; H = 308; base = PACK0; }
  else if (u < 186368) { layer = 1; rem = u - 133120; KB = 16; K = 512; H = 204; base = PACK1; }
  else if (u < 374784) { layer = 2; rem = u - 186368; KB = 23; K = 716; H = 512; base = PACK2; }
  else return;
  const int lane = rem & 63;
  const int mat = (rem >> 6) & 3;
  const int kb = (rem >> 8) % KB;
  const int nt = (rem >> 8) / KB;
  const float* W = P.w[layer * 4 + mat];
  const float* M = (mat < 2) ? P.msk[layer] : nullptr;
  const int n = nt * 16 + (lane & 15);
  const int kbase = kb * 32 + ((lane >> 4) << 3);
  ushort_t* dst = P.pack + base + (size_t)rem * 8;
#pragma unroll
  for (int j = 0; j < 8; ++j) {
    int k = kbase + j;
    float v = 0.f;
    if (n < H && k < K) {
      v = W[(size_t)n * K + k];
      if (M) v *= M[(size_t)n * K + k];
    }
    dst[j] = f2bf(v);
  }
}

// ---------------- main persistent kernel ----------------
struct MainP {
  const float* x;
  const float* gamma;
  const float* beta;
  const float* bias[12];
  const float* mu;
  const float* rstd;
  float* hi;
  float* hc;
  float* hm;
  const ushort_t* pack;
  unsigned* bar;
  float* y;
  float* hfin;
};

__device__ __forceinline__ void tile_task(
    const ushort_t* __restrict__ packL, const ushort_t* __restrict__ Alds,
    int KB, int nt, int H, int lane, int mtile, int t, bool last,
    const float* __restrict__ bp1, const float* __restrict__ bp2,
    const float* __restrict__ bpa, const float* __restrict__ bpb,
    float* __restrict__ hout, float* __restrict__ y,
    float* __restrict__ hfin, int hoff)
{
  f32x4 a0 = {0.f, 0.f, 0.f, 0.f}, a1 = a0, a2 = a0, a3 = a0;
  const ushort_t* bp = packL + (size_t)nt * KB * 2048;
  for (int kb = 0; kb < KB; ++kb) {
    short8 av = *(const short8*)(Alds + (kb * 64 + lane) * 8);
    const ushort_t* bb = bp + kb * 2048 + lane * 8;
    short8 b0 = *(const short8*)(bb);
    short8 b1 = *(const short8*)(bb + 512);
    short8 b2 = *(const short8*)(bb + 1024);
    short8 b3 = *(const short8*)(bb + 1536);
    a0 = __builtin_amdgcn_mfma_f32_16x16x32_bf16(av, b0, a0, 0, 0, 0);
    a1 = __builtin_amdgcn_mfma_f32_16x16x32_bf16(av, b1, a1, 0, 0, 0);
    a2 = __builtin_amdgcn_mfma_f32_16x16x32_bf16(av, b2, a2, 0, 0, 0);
    a3 = __builtin_amdgcn_mfma_f32_16x16x32_bf16(av, b3, a3, 0, 0, 0);
  }
  const int n = nt * 16 + (lane & 15);
  if (n < H) {
    float c1 = bp1[n], c2 = bp2[n], ca = bpa[n], cb = bpb[n];
    const int r0 = (lane >> 4) << 2;
#pragma unroll
    for (int j = 0; j < 4; ++j) {
      int brow = mtile * 16 + r0 + j;
      float s = 1.f / (1.f + __expf(-(a2[j] + ca + a3[j] + cb)));
      float f1 = 1.f - 2.f / (1.f + __expf(2.f * (a0[j] + c1)));
      float f2 = 1.f - 2.f / (1.f + __expf(2.f * (a1[j] + c2)));
      float v = f1 * (1.f - s) + s * f2;
      st_coh(hout + brow * H + n, v);
      if (y) y[((size_t)brow * T_STEPS + t) * 512 + n] = v;
      if (last) hfin[brow * 1024 + hoff + n] = v;
    }
  }
}

__global__ __launch_bounds__(256) void ncp_main(MainP P) {
  const int tid = threadIdx.x;
  const int lane = tid & 63;
  const int wv = tid >> 6;
  const int wg = blockIdx.x;
  // mtile = wg>>3: WGs with the same ntask-slice (same weight tiles) share an
  // XCD under round-robin dispatch (perf heuristic only; any bijection correct).
  const int mtile = wg >> 3;
  const int ntask = (wg & 7) * 4 + wv;  // 0..31 unique per mtile

  __shared__ __align__(16) ushort_t Alds[26 * 64 * 8];

  unsigned rnd = 0;
  for (int t = 0; t < T_STEPS; ++t) {
    const int cur = t & 1, nxt = cur ^ 1;
    float* hi_c = P.hi + cur * (64 * 308);
    float* hi_n = P.hi + nxt * (64 * 308);
    float* hc_c = P.hc + cur * (64 * 204);
    float* hc_n = P.hc + nxt * (64 * 204);
    float* hm_c = P.hm + cur * (64 * 512);
    float* hm_n = P.hm + nxt * (64 * 512);
    const bool last = (t == T_STEPS - 1);

    // ---- LAYER 0 staging: slots 0..1023 = LN(x_t) (cached loads, pipelines
    // freely); slots 1024..1663 = hi_c via batched relaxed-atomic loads:
    // issue 8 loads -> one wait -> convert+ds_write (no per-element RTT). ----
#pragma unroll
    for (int i = 0; i < 4; ++i) {
      const int p = tid + i * 256;
      const int kb = p >> 6, ln = p & 63;
      const int brow = mtile * 16 + (ln & 15);
      const int kbase = kb * 32 + ((ln >> 4) << 3);
      const float muv = P.mu[brow * T_STEPS + t];
      const float rsv = P.rstd[brow * T_STEPS + t];
      const float* xrow = P.x + ((size_t)brow * T_STEPS + t) * 512;
      short8 w;
#pragma unroll
      for (int j = 0; j < 8; ++j) {
        const int k = kbase + j;
        w[j] = f2bf((xrow[k] - muv) * rsv * P.gamma[k] + P.beta[k]);
      }
      *(short8*)(Alds + (size_t)p * 8) = w;
    }
#pragma unroll
    for (int i = 0; i < 3; ++i) {
      const int s = tid + i * 256;
      if (s < 640) {
        const int ln = s & 63;
        const int brow = mtile * 16 + (ln & 15);
        const int c0 = (s >> 6) * 32 + ((ln >> 4) << 3);
        const float* pa = hi_c + brow * 308;
        float v[8];
#pragma unroll
        for (int j = 0; j < 8; ++j)
          v[j] = (c0 + j < 308) ? ld_coh(pa + c0 + j) : 0.f;
        short8 w;
#pragma unroll
        for (int j = 0; j < 8; ++j) w[j] = f2bf(v[j]);
        *(short8*)(Alds + (size_t)(1024 + s) * 8) = w;
      }
    }
    __syncthreads();
    if (ntask < 20)
      tile_task(P.pack + PACK0, Alds, 26, ntask, 308, lane, mtile, t, last,
                P.bias[0], P.bias[1], P.bias[2], P.bias[3],
                hi_n, nullptr, P.hfin, 0);
    gbar(P.bar, (++rnd) * NWG);

    // ---- LAYER 1 staging: k<308 from hi_n, 308<=k<512 from hc_c ----
#pragma unroll
    for (int i = 0; i < 4; ++i) {
      const int s = tid + i * 256;
      const int ln = s & 63;
      const int brow = mtile * 16 + (ln & 15);
      const int kbase = (s >> 6) * 32 + ((ln >> 4) << 3);
      const float* pa = hi_n + brow * 308;
      const float* pb = hc_c + brow * 204 - 308;
      float v[8];
#pragma unroll
      for (int j = 0; j < 8; ++j) {
        const int k = kbase + j;
        v[j] = ld_coh(((k < 308) ? pa : pb) + k);
      }
      short8 w;
#pragma unroll
      for (int j = 0; j < 8; ++j) w[j] = f2bf(v[j]);
      *(short8*)(Alds + (size_t)s * 8) = w;
    }
    __syncthreads();
    if (ntask < 13)
      tile_task(P.pack + PACK1, Alds, 16, ntask, 204, lane, mtile, t, last,
                P.bias[4], P.bias[5], P.bias[6], P.bias[7],
                hc_n, nullptr, P.hfin, 308);
    gbar(P.bar, (++rnd) * NWG);

    // ---- LAYER 2 staging: k<204 from hc_n, 204<=k<716 from hm_c, else 0 ----
#pragma unroll
    for (int i = 0; i < 6; ++i) {
      const int s = tid + i * 256;
      if (s < 1472) {
        const int ln = s & 63;
        const int brow = mtile * 16 + (ln & 15);
        const int kbase = (s >> 6) * 32 + ((ln >> 4) << 3);
        const float* pa = hc_n + brow * 204;
        const float* pb = hm_c + brow * 512 - 204;
        float v[8];
#pragma unroll
        for (int j = 0; j < 8; ++j) {
          const int k = kbase + j;
          v[j] = (k < 716) ? ld_coh(((k < 204) ? pa : pb) + k) : 0.f;
        }
        short8 w;
#pragma unroll
        for (int j = 0; j < 8; ++j) w[j] = f2bf(v[j]);
        *(short8*)(Alds + (size_t)s * 8) = w;
      }
    }
    __syncthreads();
    tile_task(P.pack + PACK2, Alds, 23, ntask, 512, lane, mtile, t, last,
              P.bias[8], P.bias[9], P.bias[10], P.bias[11],
              hm_n, P.y, P.hfin, 512);
    // hm_n consumed only after next step's two gbars (each drains vmcnt) ->
    // local sync suffices here (protects LDS reuse).
    __syncthreads();
  }
}

extern "C" void kernel_launch(void* const* d_in, const int* in_sizes, int n_in,
                              void* d_out, int out_size, void* d_ws, size_t ws_size,
                              hipStream_t stream) {
  const float* x     = (const float*)d_in[27];
  const float* h0    = (const float*)d_in[28];
  const float* gamma = (const float*)d_in[29];
  const float* beta  = (const float*)d_in[30];

  char* ws = (char*)d_ws;
  unsigned* bar = (unsigned*)(ws + WS_BAR);
  float* mu   = (float*)(ws + WS_MU);
  float* rstd = (float*)(ws + WS_RSTD);
  float* hi   = (float*)(ws + WS_HI);
  float* hc   = (float*)(ws + WS_HC);
  float* hm   = (float*)(ws + WS_HM);
  ushort_t* pack = (ushort_t*)(ws + WS_PACK);

  float* y = (float*)d_out;
  float* hfin = y + (size_t)64 * 1024 * 512;

  hipMemsetAsync(bar, 0, 4096, stream);

  ln_stats<<<dim3(16384), dim3(256), 0, stream>>>(x, mu, rstd);
  init_h<<<dim3(256), dim3(256), 0, stream>>>(h0, hi, hc, hm);

  PackP pp;
  for (int l = 0; l < 3; ++l) {
    for (int m = 0; m < 4; ++m) pp.w[l * 4 + m] = (const float*)d_in[l * 9 + 2 * m];
    pp.msk[l] = (const float*)d_in[l * 9 + 8];
  }
  pp.pack = pack;
  ncp_pack<<<dim3(1464), dim3(256), 0, stream>>>(pp);

  MainP mp;
  mp.x = x; mp.gamma = gamma; mp.beta = beta;
  for (int l = 0; l < 3; ++l)
    for (int m = 0; m < 4; ++m) mp.bias[l * 4 + m] = (const float*)d_in[l * 9 + 2 * m + 1];
  mp.mu = mu; mp.rstd = rstd;
  mp.hi = hi; mp.hc = hc; mp.hm = hm;
  mp.pack = pack; mp.bar = bar;
  mp.y = y; mp.hfin = hfin;
  ncp_main<<<dim3(NWG), dim3(256), 0, stream>>>(mp);
}

// Round 5
// 38570.245 us; speedup vs baseline: 1.5623x; 1.0906x over previous
//
#include <hip/hip_runtime.h>

typedef __attribute__((ext_vector_type(8))) short short8;
typedef __attribute__((ext_vector_type(4))) float f32x4;
typedef unsigned short ushort_t;

#define T_STEPS 1024
#define NWG 32

// Padded-segment geometry (all segments multiple of 32 so kb-blocks never straddle):
//   XN 512 (16 kb) | HI 308->320 (10 kb) | HC 204->224 (7 kb) | HM 512 (16 kb)
// L0: A = XN ++ HI  KB=26  NT=20 H=308
// L1: A = HI ++ HC  KB=17  NT=13 H=204
// L2: A = HC ++ HM  KB=23  NT=32 H=512

// packed-weight bases (elements); slice = nt*KB*2048
#define PACK0 0
#define PACK1 1064960            // 20*26*2048
#define PACK2 1517568            // PACK1 + 13*17*2048

// ws offsets (bytes)
#define WS_BAR   0
#define WS_MU    4096
#define WS_RSTD  266240
#define WS_HI    528384          // 64*308*4 = 78848
#define WS_HC    607232          // 64*204*4 = 52224
#define WS_HM    659456          // 64*512*4 = 131072
#define WS_PACK  790528          // 3024896*2 = 6049792 -> ends 6840320

__device__ __forceinline__ ushort_t f2bf(float f) {
  union { float f; unsigned u; } un; un.f = f;
  unsigned r = (un.u + 0x7fffu + ((un.u >> 16) & 1u)) >> 16;
  return (ushort_t)r;
}

// h-state exchange: relaxed system-scope ops -> global_load/store_dword sc0 sc1
// (bypass L1/L2 both sides; no cache-maintenance instructions anywhere).
__device__ __forceinline__ void st_coh(float* p, float v) {
  __hip_atomic_store(p, v, __ATOMIC_RELAXED, __HIP_MEMORY_SCOPE_SYSTEM);
}
__device__ __forceinline__ float ld_coh(const float* p) {
  return __hip_atomic_load(p, __ATOMIC_RELAXED, __HIP_MEMORY_SCOPE_SYSTEM);
}

// Relaxed global barrier: per-wave store drain + relaxed counter. No release/
// acquire fences -> no buffer_wbl2/buffer_inv -> packed weights stay in L2.
__device__ __forceinline__ void gbar(unsigned* ctr, unsigned target) {
  asm volatile("s_waitcnt vmcnt(0)" ::: "memory");
  __syncthreads();
  if (threadIdx.x == 0) {
    __hip_atomic_fetch_add(ctr, 1u, __ATOMIC_RELAXED, __HIP_MEMORY_SCOPE_SYSTEM);
    while (__hip_atomic_load(ctr, __ATOMIC_RELAXED, __HIP_MEMORY_SCOPE_SYSTEM) < target)
      __builtin_amdgcn_s_sleep(1);
  }
  __syncthreads();
}

// ---------------- LayerNorm stats: one wave per (b,t) row ----------------
__global__ __launch_bounds__(256) void ln_stats(const float* __restrict__ x,
                                                float* __restrict__ mu,
                                                float* __restrict__ rstd) {
  const int row = blockIdx.x * 4 + (threadIdx.x >> 6);
  const int lane = threadIdx.x & 63;
  const float* xr = x + (size_t)row * 512;
  float4 v0 = *(const float4*)(xr + lane * 8);
  float4 v1 = *(const float4*)(xr + lane * 8 + 4);
  float s = v0.x + v0.y + v0.z + v0.w + v1.x + v1.y + v1.z + v1.w;
  float q = v0.x*v0.x + v0.y*v0.y + v0.z*v0.z + v0.w*v0.w
          + v1.x*v1.x + v1.y*v1.y + v1.z*v1.z + v1.w*v1.w;
  for (int m = 1; m <= 32; m <<= 1) {
    s += __shfl_xor(s, m, 64);
    q += __shfl_xor(q, m, 64);
  }
  if (lane == 0) {
    float mean = s * (1.f / 512.f);
    float var = q * (1.f / 512.f) - mean * mean;
    mu[row] = mean;
    rstd[row] = rsqrtf(var + 1e-5f);
  }
}

// ---------------- init hidden state from h0 (single-buffered) ----------------
__global__ void init_h(const float* __restrict__ h0, float* hi, float* hc, float* hm) {
  int i = blockIdx.x * 256 + threadIdx.x;
  if (i >= 64 * 1024) return;
  int b = i >> 10, c = i & 1023;
  float v = h0[i];
  if (c < 308) hi[b * 308 + c] = v;
  else if (c < 512) hc[b * 204 + (c - 308)] = v;
  else hm[b * 512 + (c - 512)] = v;
}

// ---------------- pack masked weights to bf16 MFMA B-frag order ----------------
// Padded K layout per layer: seg0 (padded s0p, logical s0l) ++ seg1 (logical s1l).
struct PackP {
  const float* w[12];
  const float* msk[3];
  ushort_t* pack;
};

__global__ __launch_bounds__(256) void ncp_pack(PackP P) {
  int u = blockIdx.x * 256 + threadIdx.x;
  int layer, rem, KB, K, H, s0p, s0l, s1l;
  size_t base;
  if (u < 133120)      { layer = 0; rem = u;          KB = 26; K = 820; H = 308; s0p = 512; s0l = 512; s1l = 308; base = PACK0; }
  else if (u < 189696) { layer = 1; rem = u - 133120; KB = 17; K = 512; H = 204; s0p = 320; s0l = 308; s1l = 204; base = PACK1; }
  else if (u < 378112) { layer = 2; rem = u - 189696; KB = 23; K = 716; H = 512; s0p = 224; s0l = 204; s1l = 512; base = PACK2; }
  else return;
  const int lane = rem & 63;
  const int mat = (rem >> 6) & 3;
  const int kb = (rem >> 8) % KB;
  const int nt = (rem >> 8) / KB;
  const float* W = P.w[layer * 4 + mat];
  const float* M = (mat < 2) ? P.msk[layer] : nullptr;
  const int n = nt * 16 + (lane & 15);
  const int kbase = kb * 32 + ((lane >> 4) << 3);
  ushort_t* dst = P.pack + base + (size_t)rem * 8;
#pragma unroll
  for (int j = 0; j < 8; ++j) {
    const int kp = kbase + j;
    int ko;
    if (kp < s0p) ko = (kp < s0l) ? kp : -1;
    else { const int ks = kp - s0p; ko = (ks < s1l) ? (s0l + ks) : -1; }
    float v = 0.f;
    if (n < H && ko >= 0) {
      v = W[(size_t)n * K + ko];
      if (M) v *= M[(size_t)n * K + ko];
    }
    dst[j] = f2bf(v);
  }
}

// ---------------- main persistent kernel ----------------
struct MainP {
  const float* x;
  const float* gamma;
  const float* beta;
  const float* bias[12];
  const float* mu;
  const float* rstd;
  float* hi;
  float* hc;
  float* hm;
  const ushort_t* pack;
  unsigned* bar;
  float* y;
  float* hfin;
};

// depth-4 software-pipelined MFMA span over one LDS region (compile-time KBT;
// buf indices are compile-time under full unroll -> registers, no scratch)
template<int KBT>
__device__ __forceinline__ void mfma_span(const ushort_t* __restrict__ bp,
                                          const ushort_t* __restrict__ lds, int lane,
                                          f32x4& a0, f32x4& a1, f32x4& a2, f32x4& a3) {
  const ushort_t* bb = bp + lane * 8;
  short8 buf[4][4];
#pragma unroll
  for (int kb = 0; kb < 4 && kb < KBT; ++kb) {
    const ushort_t* q = bb + (size_t)kb * 2048;
    buf[kb][0] = *(const short8*)(q);
    buf[kb][1] = *(const short8*)(q + 512);
    buf[kb][2] = *(const short8*)(q + 1024);
    buf[kb][3] = *(const short8*)(q + 1536);
  }
#pragma unroll
  for (int kb = 0; kb < KBT; ++kb) {
    short8 av = *(const short8*)(lds + (size_t)(kb * 64 + lane) * 8);
    a0 = __builtin_amdgcn_mfma_f32_16x16x32_bf16(av, buf[kb & 3][0], a0, 0, 0, 0);
    a1 = __builtin_amdgcn_mfma_f32_16x16x32_bf16(av, buf[kb & 3][1], a1, 0, 0, 0);
    a2 = __builtin_amdgcn_mfma_f32_16x16x32_bf16(av, buf[kb & 3][2], a2, 0, 0, 0);
    a3 = __builtin_amdgcn_mfma_f32_16x16x32_bf16(av, buf[kb & 3][3], a3, 0, 0, 0);
    if (kb + 4 < KBT) {
      const ushort_t* q = bb + (size_t)(kb + 4) * 2048;
      buf[kb & 3][0] = *(const short8*)(q);
      buf[kb & 3][1] = *(const short8*)(q + 512);
      buf[kb & 3][2] = *(const short8*)(q + 1024);
      buf[kb & 3][3] = *(const short8*)(q + 1536);
    }
  }
}

template<int KB1, int KB2, int H>
__device__ __forceinline__ void tile_phase(
    const ushort_t* __restrict__ packL,
    const ushort_t* __restrict__ lds1, const ushort_t* __restrict__ lds2,
    int nt, int lane, int mtile, int t, bool last,
    const float* __restrict__ bp1, const float* __restrict__ bp2,
    const float* __restrict__ bpa, const float* __restrict__ bpb,
    float* __restrict__ hout, float* __restrict__ y,
    float* __restrict__ hfin, int hoff, int HS)
{
  f32x4 a0 = {0.f, 0.f, 0.f, 0.f}, a1 = a0, a2 = a0, a3 = a0;
  const ushort_t* bp = packL + (size_t)nt * (KB1 + KB2) * 2048;
  mfma_span<KB1>(bp, lds1, lane, a0, a1, a2, a3);
  mfma_span<KB2>(bp + KB1 * 2048, lds2, lane, a0, a1, a2, a3);
  const int n = nt * 16 + (lane & 15);
  if (n < H) {
    float c1 = bp1[n], c2 = bp2[n], ca = bpa[n], cb = bpb[n];
    const int r0 = (lane >> 4) << 2;
#pragma unroll
    for (int j = 0; j < 4; ++j) {
      int brow = mtile * 16 + r0 + j;
      float s = 1.f / (1.f + __expf(-(a2[j] + ca + a3[j] + cb)));
      float f1 = 1.f - 2.f / (1.f + __expf(2.f * (a0[j] + c1)));
      float f2 = 1.f - 2.f / (1.f + __expf(2.f * (a1[j] + c2)));
      float v = f1 * (1.f - s) + s * f2;
      st_coh(hout + brow * HS + n, v);
      if (y) y[((size_t)brow * T_STEPS + t) * 512 + n] = v;
      if (last) hfin[brow * 1024 + hoff + n] = v;
    }
  }
}

// stage one padded h-segment region from a global f32 row-major [64][LS] buffer
template<int SLOTS, int LS>
__device__ __forceinline__ void stage_h(ushort_t* __restrict__ region,
                                        const float* __restrict__ hbase,
                                        int mtile, int tid) {
  constexpr int ITER = (SLOTS + 255) / 256;
#pragma unroll
  for (int i = 0; i < ITER; ++i) {
    const int s = tid + i * 256;
    if ((SLOTS & 255) == 0 || s < SLOTS) {
      const int ln = s & 63;
      const int brow = mtile * 16 + (ln & 15);
      const int c0 = (s >> 6) * 32 + ((ln >> 4) << 3);
      const float* pa = hbase + brow * LS;
      float v[8];
#pragma unroll
      for (int j = 0; j < 8; ++j) v[j] = (c0 + j < LS) ? ld_coh(pa + c0 + j) : 0.f;
      short8 w;
#pragma unroll
      for (int j = 0; j < 8; ++j) w[j] = f2bf(v[j]);
      *(short8*)(region + (size_t)s * 8) = w;
    }
  }
}

__device__ __forceinline__ void stage_xn(ushort_t* __restrict__ XN, const MainP& P,
                                         int mtile, int tid, int t) {
#pragma unroll
  for (int i = 0; i < 4; ++i) {
    const int s = tid + i * 256;
    const int ln = s & 63;
    const int brow = mtile * 16 + (ln & 15);
    const int kbase = (s >> 6) * 32 + ((ln >> 4) << 3);
    const float muv = P.mu[brow * T_STEPS + t];
    const float rsv = P.rstd[brow * T_STEPS + t];
    const float* xrow = P.x + ((size_t)brow * T_STEPS + t) * 512;
    short8 w;
#pragma unroll
    for (int j = 0; j < 8; ++j)
      w[j] = f2bf((xrow[kbase + j] - muv) * rsv * P.gamma[kbase + j] + P.beta[kbase + j]);
    *(short8*)(XN + (size_t)s * 8) = w;
  }
}

__global__ __launch_bounds__(256) void ncp_main(MainP P) {
  const int tid = threadIdx.x;
  const int lane = tid & 63;
  const int wv = tid >> 6;
  const int wg = blockIdx.x;
  // WGs with equal wg&7 share one XCD under round-robin dispatch AND share the
  // same ntask slice -> each XCD's L2 holds 1/8 of the packed weights.
  const int mtile = wg >> 3;
  const int ntask = (wg & 7) * 4 + wv;  // 0..31 unique per mtile

  __shared__ __align__(16) ushort_t Alds[3136 * 8];  // 50 KB
  ushort_t* XN = Alds;                // 1024 slots (kb 0..15)
  ushort_t* HI = Alds + 1024 * 8;     //  640 slots (10 kb)
  ushort_t* HC = Alds + 1664 * 8;     //  448 slots (7 kb)
  ushort_t* HM = Alds + 2112 * 8;     // 1024 slots (16 kb)

  // prologue: stage everything for t=0
  stage_xn(XN, P, mtile, tid, 0);
  stage_h<640, 308>(HI, P.hi, mtile, tid);
  stage_h<448, 204>(HC, P.hc, mtile, tid);
  stage_h<1024, 512>(HM, P.hm, mtile, tid);
  __syncthreads();

  unsigned rnd = 0;
  for (int t = 0; t < T_STEPS; ++t) {
    const bool last = (t == T_STEPS - 1);

    // ---- L0 compute: A = XN ++ HI -> hi ----
    if (ntask < 20)
      tile_phase<16, 10, 308>(P.pack + PACK0, XN, HI, ntask, lane, mtile, t, last,
                              P.bias[0], P.bias[1], P.bias[2], P.bias[3],
                              P.hi, nullptr, P.hfin, 0, 308);
    gbar(P.bar, (++rnd) * NWG);   // hi (and prev step's hm) now globally visible

    // ---- L1 phase: restage HI (dependent), HM (hm of t-1), XN (t+1) ----
    stage_h<640, 308>(HI, P.hi, mtile, tid);
    stage_h<1024, 512>(HM, P.hm, mtile, tid);
    stage_xn(XN, P, mtile, tid, last ? t : t + 1);
    __syncthreads();
    if (ntask < 13)
      tile_phase<10, 7, 204>(P.pack + PACK1, HI, HC, ntask, lane, mtile, t, last,
                             P.bias[4], P.bias[5], P.bias[6], P.bias[7],
                             P.hc, nullptr, P.hfin, 308, 204);
    gbar(P.bar, (++rnd) * NWG);   // hc now globally visible

    // ---- L2 phase: restage HC (dependent) ----
    stage_h<448, 204>(HC, P.hc, mtile, tid);
    __syncthreads();
    tile_phase<7, 16, 512>(P.pack + PACK2, HC, HM, ntask, lane, mtile, t, last,
                           P.bias[8], P.bias[9], P.bias[10], P.bias[11],
                           P.hm, P.y, P.hfin, 512, 512);
    // no trailing barrier: next L0 reads XN/HI staged before gbarB; hm/HM
    // produce-consume pairs are separated by next step's gbars.
  }
}

extern "C" void kernel_launch(void* const* d_in, const int* in_sizes, int n_in,
                              void* d_out, int out_size, void* d_ws, size_t ws_size,
                              hipStream_t stream) {
  const float* x     = (const float*)d_in[27];
  const float* h0    = (const float*)d_in[28];
  const float* gamma = (const float*)d_in[29];
  const float* beta  = (const float*)d_in[30];

  char* ws = (char*)d_ws;
  unsigned* bar = (unsigned*)(ws + WS_BAR);
  float* mu   = (float*)(ws + WS_MU);
  float* rstd = (float*)(ws + WS_RSTD);
  float* hi   = (float*)(ws + WS_HI);
  float* hc   = (float*)(ws + WS_HC);
  float* hm   = (float*)(ws + WS_HM);
  ushort_t* pack = (ushort_t*)(ws + WS_PACK);

  float* y = (float*)d_out;
  float* hfin = y + (size_t)64 * 1024 * 512;

  hipMemsetAsync(bar, 0, 4096, stream);

  ln_stats<<<dim3(16384), dim3(256), 0, stream>>>(x, mu, rstd);
  init_h<<<dim3(256), dim3(256), 0, stream>>>(h0, hi, hc, hm);

  PackP pp;
  for (int l = 0; l < 3; ++l) {
    for (int m = 0; m < 4; ++m) pp.w[l * 4 + m] = (const float*)d_in[l * 9 + 2 * m];
    pp.msk[l] = (const float*)d_in[l * 9 + 8];
  }
  pp.pack = pack;
  ncp_pack<<<dim3(1477), dim3(256), 0, stream>>>(pp);

  MainP mp;
  mp.x = x; mp.gamma = gamma; mp.beta = beta;
  for (int l = 0; l < 3; ++l)
    for (int m = 0; m < 4; ++m) mp.bias[l * 4 + m] = (const float*)d_in[l * 9 + 2 * m + 1];
  mp.mu = mu; mp.rstd = rstd;
  mp.hi = hi; mp.hc = hc; mp.hm = hm;
  mp.pack = pack; mp.bar = bar;
  mp.y = y; mp.hfin = hfin;
  ncp_main<<<dim3(NWG), dim3(256), 0, stream>>>(mp);
}

// Round 6
// 29726.047 us; speedup vs baseline: 2.0271x; 1.2975x over previous
//
#include <hip/hip_runtime.h>

typedef __attribute__((ext_vector_type(8))) short short8;
typedef __attribute__((ext_vector_type(4))) float f32x4;
typedef unsigned short ushort_t;

#define T_STEPS 1024
#define NWG 68

// Padded-segment geometry (segments multiple of 32 so kb-blocks never straddle):
//   XN 512 (16 kb) | HI 308->320 (10 kb) | HC 204->224 (7 kb) | HM 512 (16 kb)
// L0: A = XN ++ HI  KB=26  NT=20 H=308   (5 WGs per mtile)
// L1: A = HI ++ HC  KB=17  NT=13 H=204   (4 WGs per mtile, 3 idle waves)
// L2: A = HC ++ HM  KB=23  NT=32 H=512   (8 WGs per mtile)
// Pipeline slot s: L0 computes step s, L1 step s-1, L2 step s-2; ONE gbar/slot.

// packed-weight bases (elements); slice = nt*KB*2048
#define PACK0 0
#define PACK1 1064960            // 20*26*2048
#define PACK2 1517568            // PACK1 + 13*17*2048

// h-state element counts (f32, double-buffered by step parity)
#define HI_N 19712               // 64*308
#define HC_N 13056               // 64*204
#define HM_N 32768               // 64*512

// ws offsets (bytes)
#define WS_BAR   0
#define WS_MU    4096
#define WS_RSTD  266240
#define WS_HI    528384          // 2*78848  = 157696 -> 686080
#define WS_HC    686080          // 2*52224  = 104448 -> 790528
#define WS_HM    790528          // 2*131072 = 262144 -> 1052672
#define WS_PACK  1052672         // 6049792 -> ends 7102464

__device__ __forceinline__ ushort_t f2bf(float f) {
  union { float f; unsigned u; } un; un.f = f;
  unsigned r = (un.u + 0x7fffu + ((un.u >> 16) & 1u)) >> 16;
  return (ushort_t)r;
}

// h-state exchange: relaxed system-scope ops -> global_load/store_dword sc0 sc1
// (bypass L1/L2 both sides; no cache-maintenance instructions anywhere).
__device__ __forceinline__ void st_coh(float* p, float v) {
  __hip_atomic_store(p, v, __ATOMIC_RELAXED, __HIP_MEMORY_SCOPE_SYSTEM);
}
__device__ __forceinline__ float ld_coh(const float* p) {
  return __hip_atomic_load(p, __ATOMIC_RELAXED, __HIP_MEMORY_SCOPE_SYSTEM);
}

// Relaxed global barrier: per-wave store drain + relaxed counter. No release/
// acquire fences -> no buffer_wbl2/buffer_inv -> packed weights stay in L2.
__device__ __forceinline__ void gbar(unsigned* ctr, unsigned target) {
  asm volatile("s_waitcnt vmcnt(0)" ::: "memory");
  __syncthreads();
  if (threadIdx.x == 0) {
    __hip_atomic_fetch_add(ctr, 1u, __ATOMIC_RELAXED, __HIP_MEMORY_SCOPE_SYSTEM);
    while (__hip_atomic_load(ctr, __ATOMIC_RELAXED, __HIP_MEMORY_SCOPE_SYSTEM) < target)
      __builtin_amdgcn_s_sleep(1);
  }
  __syncthreads();
}

// ---------------- LayerNorm stats: one wave per (b,t) row ----------------
__global__ __launch_bounds__(256) void ln_stats(const float* __restrict__ x,
                                                float* __restrict__ mu,
                                                float* __restrict__ rstd) {
  const int row = blockIdx.x * 4 + (threadIdx.x >> 6);
  const int lane = threadIdx.x & 63;
  const float* xr = x + (size_t)row * 512;
  float4 v0 = *(const float4*)(xr + lane * 8);
  float4 v1 = *(const float4*)(xr + lane * 8 + 4);
  float s = v0.x + v0.y + v0.z + v0.w + v1.x + v1.y + v1.z + v1.w;
  float q = v0.x*v0.x + v0.y*v0.y + v0.z*v0.z + v0.w*v0.w
          + v1.x*v1.x + v1.y*v1.y + v1.z*v1.z + v1.w*v1.w;
  for (int m = 1; m <= 32; m <<= 1) {
    s += __shfl_xor(s, m, 64);
    q += __shfl_xor(q, m, 64);
  }
  if (lane == 0) {
    float mean = s * (1.f / 512.f);
    float var = q * (1.f / 512.f) - mean * mean;
    mu[row] = mean;
    rstd[row] = rsqrtf(var + 1e-5f);
  }
}

// ---------------- init hidden state from h0 (write BOTH parity buffers) -------
__global__ void init_h(const float* __restrict__ h0, float* hi, float* hc, float* hm) {
  int i = blockIdx.x * 256 + threadIdx.x;
  if (i >= 64 * 1024) return;
  int b = i >> 10, c = i & 1023;
  float v = h0[i];
  if (c < 308)      { hi[b*308 + c] = v;        hi[HI_N + b*308 + c] = v; }
  else if (c < 512) { hc[b*204 + (c-308)] = v;  hc[HC_N + b*204 + (c-308)] = v; }
  else              { hm[b*512 + (c-512)] = v;  hm[HM_N + b*512 + (c-512)] = v; }
}

// ---------------- pack masked weights to bf16 MFMA B-frag order ----------------
// Padded K layout per layer: seg0 (padded s0p, logical s0l) ++ seg1 (logical s1l).
struct PackP {
  const float* w[12];
  const float* msk[3];
  ushort_t* pack;
};

__global__ __launch_bounds__(256) void ncp_pack(PackP P) {
  int u = blockIdx.x * 256 + threadIdx.x;
  int layer, rem, KB, K, H, s0p, s0l, s1l;
  size_t base;
  if (u < 133120)      { layer = 0; rem = u;          KB = 26; K = 820; H = 308; s0p = 512; s0l = 512; s1l = 308; base = PACK0; }
  else if (u < 189696) { layer = 1; rem = u - 133120; KB = 17; K = 512; H = 204; s0p = 320; s0l = 308; s1l = 204; base = PACK1; }
  else if (u < 378112) { layer = 2; rem = u - 189696; KB = 23; K = 716; H = 512; s0p = 224; s0l = 204; s1l = 512; base = PACK2; }
  else return;
  const int lane = rem & 63;
  const int mat = (rem >> 6) & 3;
  const int kb = (rem >> 8) % KB;
  const int nt = (rem >> 8) / KB;
  const float* W = P.w[layer * 4 + mat];
  const float* M = (mat < 2) ? P.msk[layer] : nullptr;
  const int n = nt * 16 + (lane & 15);
  const int kbase = kb * 32 + ((lane >> 4) << 3);
  ushort_t* dst = P.pack + base + (size_t)rem * 8;
#pragma unroll
  for (int j = 0; j < 8; ++j) {
    const int kp = kbase + j;
    int ko;
    if (kp < s0p) ko = (kp < s0l) ? kp : -1;
    else { const int ks = kp - s0p; ko = (ks < s1l) ? (s0l + ks) : -1; }
    float v = 0.f;
    if (n < H && ko >= 0) {
      v = W[(size_t)n * K + ko];
      if (M) v *= M[(size_t)n * K + ko];
    }
    dst[j] = f2bf(v);
  }
}

// ---------------- main persistent kernel ----------------
struct MainP {
  const float* x;
  const float* gamma;
  const float* beta;
  const float* bias[12];
  const float* mu;
  const float* rstd;
  float* hi;
  float* hc;
  float* hm;
  const ushort_t* pack;
  unsigned* bar;
  float* y;
  float* hfin;
};

// depth-4 software-pipelined MFMA span over one LDS region (compile-time KBT;
// buf indices compile-time under full unroll -> registers, no scratch)
template<int KBT>
__device__ __forceinline__ void mfma_span(const ushort_t* __restrict__ bp,
                                          const ushort_t* __restrict__ lds, int lane,
                                          f32x4& a0, f32x4& a1, f32x4& a2, f32x4& a3) {
  const ushort_t* bb = bp + lane * 8;
  short8 buf[4][4];
#pragma unroll
  for (int kb = 0; kb < 4 && kb < KBT; ++kb) {
    const ushort_t* q = bb + (size_t)kb * 2048;
    buf[kb][0] = *(const short8*)(q);
    buf[kb][1] = *(const short8*)(q + 512);
    buf[kb][2] = *(const short8*)(q + 1024);
    buf[kb][3] = *(const short8*)(q + 1536);
  }
#pragma unroll
  for (int kb = 0; kb < KBT; ++kb) {
    short8 av = *(const short8*)(lds + (size_t)(kb * 64 + lane) * 8);
    a0 = __builtin_amdgcn_mfma_f32_16x16x32_bf16(av, buf[kb & 3][0], a0, 0, 0, 0);
    a1 = __builtin_amdgcn_mfma_f32_16x16x32_bf16(av, buf[kb & 3][1], a1, 0, 0, 0);
    a2 = __builtin_amdgcn_mfma_f32_16x16x32_bf16(av, buf[kb & 3][2], a2, 0, 0, 0);
    a3 = __builtin_amdgcn_mfma_f32_16x16x32_bf16(av, buf[kb & 3][3], a3, 0, 0, 0);
    if (kb + 4 < KBT) {
      const ushort_t* q = bb + (size_t)(kb + 4) * 2048;
      buf[kb & 3][0] = *(const short8*)(q);
      buf[kb & 3][1] = *(const short8*)(q + 512);
      buf[kb & 3][2] = *(const short8*)(q + 1024);
      buf[kb & 3][3] = *(const short8*)(q + 1536);
    }
  }
}

template<int KB1, int KB2, int H>
__device__ __forceinline__ void tile_phase(
    const ushort_t* __restrict__ packL,
    const ushort_t* __restrict__ lds1, const ushort_t* __restrict__ lds2,
    int nt, int lane, int mtile, int t, bool last,
    const float* __restrict__ bp1, const float* __restrict__ bp2,
    const float* __restrict__ bpa, const float* __restrict__ bpb,
    float* __restrict__ hout, float* __restrict__ y,
    float* __restrict__ hfin, int hoff, int HS)
{
  f32x4 a0 = {0.f, 0.f, 0.f, 0.f}, a1 = a0, a2 = a0, a3 = a0;
  const ushort_t* bp = packL + (size_t)nt * (KB1 + KB2) * 2048;
  mfma_span<KB1>(bp, lds1, lane, a0, a1, a2, a3);
  mfma_span<KB2>(bp + KB1 * 2048, lds2, lane, a0, a1, a2, a3);
  const int n = nt * 16 + (lane & 15);
  if (n < H) {
    float c1 = bp1[n], c2 = bp2[n], ca = bpa[n], cb = bpb[n];
    const int r0 = (lane >> 4) << 2;
#pragma unroll
    for (int j = 0; j < 4; ++j) {
      int brow = mtile * 16 + r0 + j;
      float s = 1.f / (1.f + __expf(-(a2[j] + ca + a3[j] + cb)));
      float f1 = 1.f - 2.f / (1.f + __expf(2.f * (a0[j] + c1)));
      float f2 = 1.f - 2.f / (1.f + __expf(2.f * (a1[j] + c2)));
      float v = f1 * (1.f - s) + s * f2;
      st_coh(hout + brow * HS + n, v);
      if (y) y[((size_t)brow * T_STEPS + t) * 512 + n] = v;
      if (last) hfin[brow * 1024 + hoff + n] = v;
    }
  }
}

// stage one or two padded h-segments; ALL loads issued before any use so the
// whole slot's staging costs ~one L3 round trip.
template<int S1, int LS1, int S2, int LS2>
__device__ __forceinline__ void stage_hh(ushort_t* __restrict__ r1, const float* __restrict__ h1,
                                         ushort_t* __restrict__ r2, const float* __restrict__ h2,
                                         int mt, int tid) {
  constexpr int I1 = (S1 + 255) / 256;
  constexpr int I2 = (S2 + 255) / 256;
  float v1[I1][8];
  float v2[I2 ? I2 : 1][8];
#pragma unroll
  for (int i = 0; i < I1; ++i) {
    const int s = tid + i * 256;
    if ((S1 & 255) == 0 || s < S1) {
      const int ln = s & 63;
      const int brow = mt * 16 + (ln & 15);
      const int c0 = (s >> 6) * 32 + ((ln >> 4) << 3);
      const float* pa = h1 + brow * LS1;
#pragma unroll
      for (int j = 0; j < 8; ++j) v1[i][j] = (c0 + j < LS1) ? ld_coh(pa + c0 + j) : 0.f;
    }
  }
  if constexpr (S2 > 0) {
#pragma unroll
    for (int i = 0; i < I2; ++i) {
      const int s = tid + i * 256;
      if ((S2 & 255) == 0 || s < S2) {
        const int ln = s & 63;
        const int brow = mt * 16 + (ln & 15);
        const int c0 = (s >> 6) * 32 + ((ln >> 4) << 3);
        const float* pa = h2 + brow * LS2;
#pragma unroll
        for (int j = 0; j < 8; ++j) v2[i][j] = (c0 + j < LS2) ? ld_coh(pa + c0 + j) : 0.f;
      }
    }
  }
#pragma unroll
  for (int i = 0; i < I1; ++i) {
    const int s = tid + i * 256;
    if ((S1 & 255) == 0 || s < S1) {
      short8 w;
#pragma unroll
      for (int j = 0; j < 8; ++j) w[j] = f2bf(v1[i][j]);
      *(short8*)(r1 + (size_t)s * 8) = w;
    }
  }
  if constexpr (S2 > 0) {
#pragma unroll
    for (int i = 0; i < I2; ++i) {
      const int s = tid + i * 256;
      if ((S2 & 255) == 0 || s < S2) {
        short8 w;
#pragma unroll
        for (int j = 0; j < 8; ++j) w[j] = f2bf(v2[i][j]);
        *(short8*)(r2 + (size_t)s * 8) = w;
      }
    }
  }
}

__device__ __forceinline__ void stage_xn(ushort_t* __restrict__ XN, const MainP& P,
                                         int mtile, int tid, int t) {
#pragma unroll
  for (int i = 0; i < 4; ++i) {
    const int s = tid + i * 256;
    const int ln = s & 63;
    const int brow = mtile * 16 + (ln & 15);
    const int kbase = (s >> 6) * 32 + ((ln >> 4) << 3);
    const float muv = P.mu[brow * T_STEPS + t];
    const float rsv = P.rstd[brow * T_STEPS + t];
    const float* xrow = P.x + ((size_t)brow * T_STEPS + t) * 512;
    short8 w;
#pragma unroll
    for (int j = 0; j < 8; ++j)
      w[j] = f2bf((xrow[kbase + j] - muv) * rsv * P.gamma[kbase + j] + P.beta[kbase + j]);
    *(short8*)(XN + (size_t)s * 8) = w;
  }
}

__global__ __launch_bounds__(256) void ncp_main(MainP P) {
  const int tid = threadIdx.x;
  const int lane = tid & 63;
  const int wv = tid >> 6;
  const int wg = blockIdx.x;
  const int mt = wg / 17;        // 0..3 (16 batch rows each)
  const int r  = wg % 17;        // 0..4: L0, 5..8: L1, 9..16: L2

  __shared__ __align__(16) ushort_t Alds[2688 * 8];  // 42 KB max (L0 layout)
  // L0: XN parity0 [0..1023], XN parity1 [1024..2047], HI [2048..2687]
  // L1: HI [0..639], HC [640..1087]
  // L2: HC [0..447], HM [448..1471]

  if (r < 5) stage_xn(Alds, P, mt, tid, 0);  // prologue XN(0) into parity-0

  unsigned rnd = 0;
  for (int s = 0; s < T_STEPS + 2; ++s) {
    if (r < 5) {             // ---- L0: compute step s ----
      if (s < T_STEPS) {
        ushort_t* HIl = Alds + 2048 * 8;
        stage_hh<640, 308, 0, 0>(HIl, P.hi + ((s - 1) & 1) * HI_N, nullptr, nullptr, mt, tid);
        __syncthreads();
        ushort_t* XNc = Alds + (s & 1) * (1024 * 8);
        tile_phase<16, 10, 308>(P.pack + PACK0, XNc, HIl, r * 4 + wv, lane, mt, s,
                                s == T_STEPS - 1,
                                P.bias[0], P.bias[1], P.bias[2], P.bias[3],
                                P.hi + (s & 1) * HI_N, nullptr, P.hfin, 0, 308);
        if (s + 1 < T_STEPS)
          stage_xn(Alds + ((s + 1) & 1) * (1024 * 8), P, mt, tid, s + 1);
      }
    } else if (r < 9) {      // ---- L1: compute step s-1 ----
      if (s >= 1 && s <= T_STEPS) {
        const int u = s - 1;
        ushort_t* HIr = Alds;
        ushort_t* HCr = Alds + 640 * 8;
        stage_hh<640, 308, 448, 204>(HIr, P.hi + (u & 1) * HI_N,
                                     HCr, P.hc + ((u - 1) & 1) * HC_N, mt, tid);
        __syncthreads();
        const int nt = (r - 5) * 4 + wv;
        if (nt < 13)
          tile_phase<10, 7, 204>(P.pack + PACK1, HIr, HCr, nt, lane, mt, u,
                                 u == T_STEPS - 1,
                                 P.bias[4], P.bias[5], P.bias[6], P.bias[7],
                                 P.hc + (u & 1) * HC_N, nullptr, P.hfin, 308, 204);
      }
    } else {                 // ---- L2: compute step s-2 ----
      if (s >= 2) {
        const int w = s - 2;
        ushort_t* HCr = Alds;
        ushort_t* HMr = Alds + 448 * 8;
        stage_hh<448, 204, 1024, 512>(HCr, P.hc + (w & 1) * HC_N,
                                      HMr, P.hm + ((w - 1) & 1) * HM_N, mt, tid);
        __syncthreads();
        tile_phase<7, 16, 512>(P.pack + PACK2, HCr, HMr, (r - 9) * 4 + wv, lane, mt, w,
                               w == T_STEPS - 1,
                               P.bias[8], P.bias[9], P.bias[10], P.bias[11],
                               P.hm + (w & 1) * HM_N, P.y, P.hfin, 512, 512);
      }
    }
    gbar(P.bar, (++rnd) * NWG);
  }
}

extern "C" void kernel_launch(void* const* d_in, const int* in_sizes, int n_in,
                              void* d_out, int out_size, void* d_ws, size_t ws_size,
                              hipStream_t stream) {
  const float* x     = (const float*)d_in[27];
  const float* h0    = (const float*)d_in[28];
  const float* gamma = (const float*)d_in[29];
  const float* beta  = (const float*)d_in[30];

  char* ws = (char*)d_ws;
  unsigned* bar = (unsigned*)(ws + WS_BAR);
  float* mu   = (float*)(ws + WS_MU);
  float* rstd = (float*)(ws + WS_RSTD);
  float* hi   = (float*)(ws + WS_HI);
  float* hc   = (float*)(ws + WS_HC);
  float* hm   = (float*)(ws + WS_HM);
  ushort_t* pack = (ushort_t*)(ws + WS_PACK);

  float* y = (float*)d_out;
  float* hfin = y + (size_t)64 * 1024 * 512;

  hipMemsetAsync(bar, 0, 4096, stream);

  ln_stats<<<dim3(16384), dim3(256), 0, stream>>>(x, mu, rstd);
  init_h<<<dim3(256), dim3(256), 0, stream>>>(h0, hi, hc, hm);

  PackP pp;
  for (int l = 0; l < 3; ++l) {
    for (int m = 0; m < 4; ++m) pp.w[l * 4 + m] = (const float*)d_in[l * 9 + 2 * m];
    pp.msk[l] = (const float*)d_in[l * 9 + 8];
  }
  pp.pack = pack;
  ncp_pack<<<dim3(1477), dim3(256), 0, stream>>>(pp);

  MainP mp;
  mp.x = x; mp.gamma = gamma; mp.beta = beta;
  for (int l = 0; l < 3; ++l)
    for (int m = 0; m < 4; ++m) mp.bias[l * 4 + m] = (const float*)d_in[l * 9 + 2 * m + 1];
  mp.mu = mu; mp.rstd = rstd;
  mp.hi = hi; mp.hc = hc; mp.hm = hm;
  mp.pack = pack; mp.bar = bar;
  mp.y = y; mp.hfin = hfin;
  ncp_main<<<dim3(NWG), dim3(256), 0, stream>>>(mp);
}

// Round 7
// 23135.280 us; speedup vs baseline: 2.6046x; 1.2849x over previous
//
#include <hip/hip_runtime.h>

typedef __attribute__((ext_vector_type(8))) short short8;
typedef __attribute__((ext_vector_type(4))) float f32x4;
typedef unsigned short ushort_t;
typedef unsigned long long u64_t;

#define T_STEPS 1024
#define NWG 68

// Padded-segment geometry (segments multiple of 32 so kb-blocks never straddle):
//   XN 512 (16 kb) | HI 308->320 (10 kb) | HC 204->224 (7 kb) | HM 512 (16 kb)
// L0: A = XN ++ HI  KB=26  NT=20 H=308   (5 WGs per mtile)
// L1: A = HI ++ HC  KB=17  NT=13 H=204   (4 WGs per mtile, 3 idle waves)
// L2: A = HC ++ HM  KB=23  NT=32 H=512   (8 WGs per mtile)
// Pipeline slot s: L0 computes step s, L1 step s-1, L2 step s-2; ONE gbar/slot.
// h-state: bf16 LINEAR padded rows, parity double-buffered, exchanged through
// the coherent point (sc0 sc1 both sides; no cache maintenance anywhere).

#define PACK0 0
#define PACK1 1064960            // 20*26*2048
#define PACK2 1517568            // PACK1 + 13*17*2048

// bf16 h-state: elements per parity
#define HI_P (64*320)
#define HC_P (64*224)
#define HM_P (64*512)

// ws offsets (bytes)
#define WS_BAR   0
#define WS_MU    4096
#define WS_RSTD  266240
#define WS_HI    528384          // 2*HI_P*2 = 81920  -> 610304
#define WS_HC    610304          // 2*HC_P*2 = 57344  -> 667648
#define WS_HM    667648          // 2*HM_P*2 = 131072 -> 798720
#define WS_PACK  798720          // 6049792 -> ends 6848512

__device__ __forceinline__ ushort_t f2bf(float f) {
  union { float f; unsigned u; } un; un.f = f;
  unsigned r = (un.u + 0x7fffu + ((un.u >> 16) & 1u)) >> 16;
  return (ushort_t)r;
}

// coherent-point exchange: relaxed system-scope atomics -> sc0 sc1, no fences
__device__ __forceinline__ void st2(ushort_t* p, ushort_t v) {
  __hip_atomic_store(p, v, __ATOMIC_RELAXED, __HIP_MEMORY_SCOPE_SYSTEM);
}
__device__ __forceinline__ u64_t ld8(const ushort_t* p) {
  return __hip_atomic_load((const u64_t*)p, __ATOMIC_RELAXED, __HIP_MEMORY_SCOPE_SYSTEM);
}

// Relaxed global barrier: per-wave store drain + relaxed counter. No release/
// acquire fences -> no buffer_wbl2/buffer_inv -> packed weights stay in L2.
__device__ __forceinline__ void gbar(unsigned* ctr, unsigned target) {
  asm volatile("s_waitcnt vmcnt(0)" ::: "memory");
  __syncthreads();
  if (threadIdx.x == 0) {
    __hip_atomic_fetch_add(ctr, 1u, __ATOMIC_RELAXED, __HIP_MEMORY_SCOPE_SYSTEM);
    while (__hip_atomic_load(ctr, __ATOMIC_RELAXED, __HIP_MEMORY_SCOPE_SYSTEM) < target)
      __builtin_amdgcn_s_sleep(1);
  }
  __syncthreads();
}

// ---------------- LayerNorm stats: one wave per (b,t) row ----------------
__global__ __launch_bounds__(256) void ln_stats(const float* __restrict__ x,
                                                float* __restrict__ mu,
                                                float* __restrict__ rstd) {
  const int row = blockIdx.x * 4 + (threadIdx.x >> 6);
  const int lane = threadIdx.x & 63;
  const float* xr = x + (size_t)row * 512;
  float4 v0 = *(const float4*)(xr + lane * 8);
  float4 v1 = *(const float4*)(xr + lane * 8 + 4);
  float s = v0.x + v0.y + v0.z + v0.w + v1.x + v1.y + v1.z + v1.w;
  float q = v0.x*v0.x + v0.y*v0.y + v0.z*v0.z + v0.w*v0.w
          + v1.x*v1.x + v1.y*v1.y + v1.z*v1.z + v1.w*v1.w;
  for (int m = 1; m <= 32; m <<= 1) {
    s += __shfl_xor(s, m, 64);
    q += __shfl_xor(q, m, 64);
  }
  if (lane == 0) {
    float mean = s * (1.f / 512.f);
    float var = q * (1.f / 512.f) - mean * mean;
    mu[row] = mean;
    rstd[row] = rsqrtf(var + 1e-5f);
  }
}

// ---------------- init hidden state: bf16 linear padded, BOTH parities -------
__global__ void init_h(const float* __restrict__ h0,
                       ushort_t* hi, ushort_t* hc, ushort_t* hm) {
  int i = blockIdx.x * 256 + threadIdx.x;
  if (i >= 64 * 1056) return;
  int b = i / 1056, c = i % 1056;
  if (c < 320) {
    ushort_t v = (c < 308) ? f2bf(h0[b * 1024 + c]) : 0;
    st2(hi + b * 320 + c, v); st2(hi + HI_P + b * 320 + c, v);
  } else if (c < 544) {
    int col = c - 320;
    ushort_t v = (col < 204) ? f2bf(h0[b * 1024 + 308 + col]) : 0;
    st2(hc + b * 224 + col, v); st2(hc + HC_P + b * 224 + col, v);
  } else {
    int col = c - 544;
    ushort_t v = f2bf(h0[b * 1024 + 512 + col]);
    st2(hm + b * 512 + col, v); st2(hm + HM_P + b * 512 + col, v);
  }
}

// ---------------- pack masked weights to bf16 MFMA B-frag order ----------------
struct PackP {
  const float* w[12];
  const float* msk[3];
  ushort_t* pack;
};

__global__ __launch_bounds__(256) void ncp_pack(PackP P) {
  int u = blockIdx.x * 256 + threadIdx.x;
  int layer, rem, KB, K, H, s0p, s0l, s1l;
  size_t base;
  if (u < 133120)      { layer = 0; rem = u;          KB = 26; K = 820; H = 308; s0p = 512; s0l = 512; s1l = 308; base = PACK0; }
  else if (u < 189696) { layer = 1; rem = u - 133120; KB = 17; K = 512; H = 204; s0p = 320; s0l = 308; s1l = 204; base = PACK1; }
  else if (u < 378112) { layer = 2; rem = u - 189696; KB = 23; K = 716; H = 512; s0p = 224; s0l = 204; s1l = 512; base = PACK2; }
  else return;
  const int lane = rem & 63;
  const int mat = (rem >> 6) & 3;
  const int kb = (rem >> 8) % KB;
  const int nt = (rem >> 8) / KB;
  const float* W = P.w[layer * 4 + mat];
  const float* M = (mat < 2) ? P.msk[layer] : nullptr;
  const int n = nt * 16 + (lane & 15);
  const int kbase = kb * 32 + ((lane >> 4) << 3);
  ushort_t* dst = P.pack + base + (size_t)rem * 8;
#pragma unroll
  for (int j = 0; j < 8; ++j) {
    const int kp = kbase + j;
    int ko;
    if (kp < s0p) ko = (kp < s0l) ? kp : -1;
    else { const int ks = kp - s0p; ko = (ks < s1l) ? (s0l + ks) : -1; }
    float v = 0.f;
    if (n < H && ko >= 0) {
      v = W[(size_t)n * K + ko];
      if (M) v *= M[(size_t)n * K + ko];
    }
    dst[j] = f2bf(v);
  }
}

// ---------------- main persistent kernel ----------------
struct MainP {
  const float* x;
  const float* gamma;
  const float* beta;
  const float* bias[12];
  const float* mu;
  const float* rstd;
  ushort_t* hi;
  ushort_t* hc;
  ushort_t* hm;
  const ushort_t* pack;
  unsigned* bar;
  float* y;
  float* hfin;
};

// depth-4 software-pipelined MFMA span over one LDS region
template<int KBT>
__device__ __forceinline__ void mfma_span(const ushort_t* __restrict__ bp,
                                          const ushort_t* __restrict__ lds, int lane,
                                          f32x4& a0, f32x4& a1, f32x4& a2, f32x4& a3) {
  const ushort_t* bb = bp + lane * 8;
  short8 buf[4][4];
#pragma unroll
  for (int kb = 0; kb < 4 && kb < KBT; ++kb) {
    const ushort_t* q = bb + (size_t)kb * 2048;
    buf[kb][0] = *(const short8*)(q);
    buf[kb][1] = *(const short8*)(q + 512);
    buf[kb][2] = *(const short8*)(q + 1024);
    buf[kb][3] = *(const short8*)(q + 1536);
  }
#pragma unroll
  for (int kb = 0; kb < KBT; ++kb) {
    short8 av = *(const short8*)(lds + (size_t)(kb * 64 + lane) * 8);
    a0 = __builtin_amdgcn_mfma_f32_16x16x32_bf16(av, buf[kb & 3][0], a0, 0, 0, 0);
    a1 = __builtin_amdgcn_mfma_f32_16x16x32_bf16(av, buf[kb & 3][1], a1, 0, 0, 0);
    a2 = __builtin_amdgcn_mfma_f32_16x16x32_bf16(av, buf[kb & 3][2], a2, 0, 0, 0);
    a3 = __builtin_amdgcn_mfma_f32_16x16x32_bf16(av, buf[kb & 3][3], a3, 0, 0, 0);
    if (kb + 4 < KBT) {
      const ushort_t* q = bb + (size_t)(kb + 4) * 2048;
      buf[kb & 3][0] = *(const short8*)(q);
      buf[kb & 3][1] = *(const short8*)(q + 512);
      buf[kb & 3][2] = *(const short8*)(q + 1024);
      buf[kb & 3][3] = *(const short8*)(q + 1536);
    }
  }
}

template<int KB1, int KB2, int H, int STP>
__device__ __forceinline__ void tile_phase(
    const ushort_t* __restrict__ packL,
    const ushort_t* __restrict__ lds1, const ushort_t* __restrict__ lds2,
    int nt, int lane, int mtile, int t, bool last,
    const float* __restrict__ bp1, const float* __restrict__ bp2,
    const float* __restrict__ bpa, const float* __restrict__ bpb,
    ushort_t* __restrict__ hout, float* __restrict__ y,
    float* __restrict__ hfin, int hoff)
{
  f32x4 a0 = {0.f, 0.f, 0.f, 0.f}, a1 = a0, a2 = a0, a3 = a0;
  const ushort_t* bp = packL + (size_t)nt * (KB1 + KB2) * 2048;
  mfma_span<KB1>(bp, lds1, lane, a0, a1, a2, a3);
  mfma_span<KB2>(bp + KB1 * 2048, lds2, lane, a0, a1, a2, a3);
  const int n = nt * 16 + (lane & 15);
  if (n < H) {
    float c1 = bp1[n], c2 = bp2[n], ca = bpa[n], cb = bpb[n];
    const int r0 = (lane >> 4) << 2;
#pragma unroll
    for (int j = 0; j < 4; ++j) {
      int brow = mtile * 16 + r0 + j;
      float s = 1.f / (1.f + __expf(-(a2[j] + ca + a3[j] + cb)));
      float f1 = 1.f - 2.f / (1.f + __expf(2.f * (a0[j] + c1)));
      float f2 = 1.f - 2.f / (1.f + __expf(2.f * (a1[j] + c2)));
      float v = f1 * (1.f - s) + s * f2;
      st2(hout + (size_t)brow * STP + n, f2bf(v));
      if (y) y[((size_t)brow * T_STEPS + t) * 512 + n] = v;
      if (last) hfin[brow * 1024 + hoff + n] = v;
    }
  }
}

// stage up to two bf16 padded segments (h already bf16 & A-compatible): per
// 8B-unit u: slot=u>>1, row=slot&15, c = (slot>>6)*32 + ((slot>>4)&3)*8 + (u&1)*4.
// Wave-level access is 16 rows x 32B contiguous -> fully coalesced; all loads
// issued before any LDS write -> ~1 coherent-point round trip per slot.
template<int S1, int ST1, int S2, int ST2>
__device__ __forceinline__ void stage2(ushort_t* __restrict__ r1, const ushort_t* __restrict__ h1,
                                       ushort_t* __restrict__ r2, const ushort_t* __restrict__ h2,
                                       int tid) {
  constexpr int U1 = S1 * 2, U2 = S2 * 2;
  constexpr int I1 = (U1 + 255) / 256;
  constexpr int I2 = (U2 + 255) / 256;
  u64_t a[I1];
  u64_t b[I2 > 0 ? I2 : 1];
#pragma unroll
  for (int i = 0; i < I1; ++i) {
    const int u = tid + i * 256;
    if ((U1 & 255) == 0 || u < U1) {
      const int slot = u >> 1;
      a[i] = ld8(h1 + (slot & 15) * ST1 + (slot >> 6) * 32 + ((slot >> 4) & 3) * 8 + (u & 1) * 4);
    }
  }
  if constexpr (S2 > 0) {
#pragma unroll
    for (int i = 0; i < I2; ++i) {
      const int u = tid + i * 256;
      if ((U2 & 255) == 0 || u < U2) {
        const int slot = u >> 1;
        b[i] = ld8(h2 + (slot & 15) * ST2 + (slot >> 6) * 32 + ((slot >> 4) & 3) * 8 + (u & 1) * 4);
      }
    }
  }
#pragma unroll
  for (int i = 0; i < I1; ++i) {
    const int u = tid + i * 256;
    if ((U1 & 255) == 0 || u < U1) *(u64_t*)(r1 + (size_t)u * 4) = a[i];
  }
  if constexpr (S2 > 0) {
#pragma unroll
    for (int i = 0; i < I2; ++i) {
      const int u = tid + i * 256;
      if ((U2 & 255) == 0 || u < U2) *(u64_t*)(r2 + (size_t)u * 4) = b[i];
    }
  }
}

__device__ __forceinline__ void stage_xn(ushort_t* __restrict__ XN, const MainP& P,
                                         int mtile, int tid, int t) {
#pragma unroll
  for (int i = 0; i < 4; ++i) {
    const int s = tid + i * 256;
    const int ln = s & 63;
    const int brow = mtile * 16 + (ln & 15);
    const int kbase = (s >> 6) * 32 + ((ln >> 4) << 3);
    const float muv = P.mu[brow * T_STEPS + t];
    const float rsv = P.rstd[brow * T_STEPS + t];
    const float* xrow = P.x + ((size_t)brow * T_STEPS + t) * 512;
    short8 w;
#pragma unroll
    for (int j = 0; j < 8; ++j)
      w[j] = f2bf((xrow[kbase + j] - muv) * rsv * P.gamma[kbase + j] + P.beta[kbase + j]);
    *(short8*)(XN + (size_t)s * 8) = w;
  }
}

__global__ __launch_bounds__(256) void ncp_main(MainP P) {
  const int tid = threadIdx.x;
  const int lane = tid & 63;
  const int wv = tid >> 6;
  const int wg = blockIdx.x;
  const int mt = wg / 17;        // 0..3 (16 batch rows each)
  const int r  = wg % 17;        // 0..4: L0, 5..8: L1, 9..16: L2

  __shared__ __align__(16) ushort_t Alds[2688 * 8];  // 42 KB max (L0 layout)
  // L0: XN parity0 [0..1023], XN parity1 [1024..2047], HI [2048..2687]
  // L1: HI [0..639], HC [640..1087]
  // L2: HC [0..447], HM [448..1471]

  if (r < 5) stage_xn(Alds, P, mt, tid, 0);  // prologue XN(0) into parity-0

  unsigned rnd = 0;
  for (int s = 0; s < T_STEPS + 2; ++s) {
    if (r < 5) {             // ---- L0: compute step s ----
      if (s < T_STEPS) {
        ushort_t* HIl = Alds + 2048 * 8;
        stage2<640, 320, 0, 0>(HIl, P.hi + (((s - 1) & 1) * 64 + mt * 16) * 320,
                               nullptr, nullptr, tid);
        __syncthreads();
        ushort_t* XNc = Alds + (s & 1) * (1024 * 8);
        tile_phase<16, 10, 308, 320>(P.pack + PACK0, XNc, HIl, r * 4 + wv, lane, mt, s,
                                     s == T_STEPS - 1,
                                     P.bias[0], P.bias[1], P.bias[2], P.bias[3],
                                     P.hi + (s & 1) * HI_P, nullptr, P.hfin, 0);
        if (s + 1 < T_STEPS)
          stage_xn(Alds + ((s + 1) & 1) * (1024 * 8), P, mt, tid, s + 1);
      }
    } else if (r < 9) {      // ---- L1: compute step s-1 ----
      if (s >= 1 && s <= T_STEPS) {
        const int u = s - 1;
        ushort_t* HIr = Alds;
        ushort_t* HCr = Alds + 640 * 8;
        stage2<640, 320, 448, 224>(HIr, P.hi + ((u & 1) * 64 + mt * 16) * 320,
                                   HCr, P.hc + ((((u - 1) & 1)) * 64 + mt * 16) * 224, tid);
        __syncthreads();
        const int nt = (r - 5) * 4 + wv;
        if (nt < 13)
          tile_phase<10, 7, 204, 224>(P.pack + PACK1, HIr, HCr, nt, lane, mt, u,
                                      u == T_STEPS - 1,
                                      P.bias[4], P.bias[5], P.bias[6], P.bias[7],
                                      P.hc + (u & 1) * HC_P, nullptr, P.hfin, 308);
      }
    } else {                 // ---- L2: compute step s-2 ----
      if (s >= 2) {
        const int w = s - 2;
        ushort_t* HCr = Alds;
        ushort_t* HMr = Alds + 448 * 8;
        stage2<448, 224, 1024, 512>(HCr, P.hc + ((w & 1) * 64 + mt * 16) * 224,
                                    HMr, P.hm + (((w - 1) & 1) * 64 + mt * 16) * 512, tid);
        __syncthreads();
        tile_phase<7, 16, 512, 512>(P.pack + PACK2, HCr, HMr, (r - 9) * 4 + wv, lane, mt, w,
                                    w == T_STEPS - 1,
                                    P.bias[8], P.bias[9], P.bias[10], P.bias[11],
                                    P.hm + (w & 1) * HM_P, P.y, P.hfin, 512);
      }
    }
    gbar(P.bar, (++rnd) * NWG);
  }
}

extern "C" void kernel_launch(void* const* d_in, const int* in_sizes, int n_in,
                              void* d_out, int out_size, void* d_ws, size_t ws_size,
                              hipStream_t stream) {
  const float* x     = (const float*)d_in[27];
  const float* h0    = (const float*)d_in[28];
  const float* gamma = (const float*)d_in[29];
  const float* beta  = (const float*)d_in[30];

  char* ws = (char*)d_ws;
  unsigned* bar = (unsigned*)(ws + WS_BAR);
  float* mu   = (float*)(ws + WS_MU);
  float* rstd = (float*)(ws + WS_RSTD);
  ushort_t* hi = (ushort_t*)(ws + WS_HI);
  ushort_t* hc = (ushort_t*)(ws + WS_HC);
  ushort_t* hm = (ushort_t*)(ws + WS_HM);
  ushort_t* pack = (ushort_t*)(ws + WS_PACK);

  float* y = (float*)d_out;
  float* hfin = y + (size_t)64 * 1024 * 512;

  hipMemsetAsync(bar, 0, 4096, stream);

  ln_stats<<<dim3(16384), dim3(256), 0, stream>>>(x, mu, rstd);
  init_h<<<dim3(264), dim3(256), 0, stream>>>(h0, hi, hc, hm);

  PackP pp;
  for (int l = 0; l < 3; ++l) {
    for (int m = 0; m < 4; ++m) pp.w[l * 4 + m] = (const float*)d_in[l * 9 + 2 * m];
    pp.msk[l] = (const float*)d_in[l * 9 + 8];
  }
  pp.pack = pack;
  ncp_pack<<<dim3(1477), dim3(256), 0, stream>>>(pp);

  MainP mp;
  mp.x = x; mp.gamma = gamma; mp.beta = beta;
  for (int l = 0; l < 3; ++l)
    for (int m = 0; m < 4; ++m) mp.bias[l * 4 + m] = (const float*)d_in[l * 9 + 2 * m + 1];
  mp.mu = mu; mp.rstd = rstd;
  mp.hi = hi; mp.hc = hc; mp.hm = hm;
  mp.pack = pack; mp.bar = bar;
  mp.y = y; mp.hfin = hfin;
  ncp_main<<<dim3(NWG), dim3(256), 0, stream>>>(mp);
}

// Round 8
// 20720.552 us; speedup vs baseline: 2.9081x; 1.1165x over previous
//
#include <hip/hip_runtime.h>

typedef __attribute__((ext_vector_type(8))) short short8;
typedef __attribute__((ext_vector_type(4))) float f32x4;
typedef unsigned short ushort_t;
typedef unsigned long long u64_t;

#define T_STEPS 1024
#define NWG 68

// Padded-segment geometry (segments multiple of 32 so kb-blocks never straddle):
//   XN 512 (16 kb) | HI 308->320 (10 kb) | HC 204->224 (7 kb) | HM 512 (16 kb)
// L0: A = XN ++ HI  KB=26  NT=20 H=308   (5 WGs per mtile, r=0..4)
// L1: A = HI ++ HC  KB=17  NT=13 H=204   (4 WGs per mtile, r=5..8)
// L2: A = HC ++ HM  KB=23  NT=32 H=512   (8 WGs per mtile, r=9..16)
// Pipeline slot s: L0 computes step s, L1 step s-1, L2 step s-2.
// Sync: DATAFLOW FLAGS (no global barrier, no RMW atomics). Per WG:
//   wflag = s+1 after its slot-s h-writes are drained (vmcnt0 + syncthreads)
//   rflag = s+1 after its slot-s staging loads are consumed into LDS
// Waits at slot s (all within the SAME mtile; contiguous WG ranges):
//   L0: wflag[0,5) >= s   (hi(s-1) producers)  + rflag[0,9)  >= s (hi WAR)
//   L1: wflag[0,9) >= s   (hi,hc producers)    + rflag[5,17) >= s (hc WAR)
//   L2: wflag[5,17) >= s  (hc,hm producers)    + rflag[9,17) >= s (hm WAR)
// RAW: hi(s-1) by L0@s-1 (w>=s), hc(s-2) by L1@s-1 (w>=s), hm(s-3) by L2@s-1.
// WAR: hi parity s&1 old content hi(s-2) read at s-1 by L0,L1 (r>=s); hc by
// L1,L2; hm by L2. Max skew L0>=L1>=L2>=L0-2, buffers 2-deep -> safe.

#define PACK0 0
#define PACK1 1064960            // 20*26*2048
#define PACK2 1517568            // PACK1 + 13*17*2048

// bf16 h-state: elements per parity
#define HI_P (64*320)
#define HC_P (64*224)
#define HM_P (64*512)

// ws offsets (bytes)
#define WS_BAR   0
#define WS_MU    4096
#define WS_RSTD  266240
#define WS_HI    528384          // 2*HI_P*2 = 81920  -> 610304
#define WS_HC    610304          // 2*HC_P*2 = 57344  -> 667648
#define WS_HM    667648          // 2*HM_P*2 = 131072 -> 798720
#define WS_PACK  798720          // 6049792 -> ends 6848512

__device__ __forceinline__ ushort_t f2bf(float f) {
  union { float f; unsigned u; } un; un.f = f;
  unsigned r = (un.u + 0x7fffu + ((un.u >> 16) & 1u)) >> 16;
  return (ushort_t)r;
}

// coherent-point exchange: relaxed system-scope atomics -> sc0 sc1, no fences
__device__ __forceinline__ void st2(ushort_t* p, ushort_t v) {
  __hip_atomic_store(p, v, __ATOMIC_RELAXED, __HIP_MEMORY_SCOPE_SYSTEM);
}
__device__ __forceinline__ u64_t ld8(const ushort_t* p) {
  return __hip_atomic_load((const u64_t*)p, __ATOMIC_RELAXED, __HIP_MEMORY_SCOPE_SYSTEM);
}
__device__ __forceinline__ unsigned ldf(const unsigned* p) {
  return __hip_atomic_load(p, __ATOMIC_RELAXED, __HIP_MEMORY_SCOPE_SYSTEM);
}
__device__ __forceinline__ void stf(unsigned* p, unsigned v) {
  __hip_atomic_store(p, v, __ATOMIC_RELAXED, __HIP_MEMORY_SCOPE_SYSTEM);
}

// ---------------- LayerNorm stats: one wave per (b,t) row ----------------
__global__ __launch_bounds__(256) void ln_stats(const float* __restrict__ x,
                                                float* __restrict__ mu,
                                                float* __restrict__ rstd) {
  const int row = blockIdx.x * 4 + (threadIdx.x >> 6);
  const int lane = threadIdx.x & 63;
  const float* xr = x + (size_t)row * 512;
  float4 v0 = *(const float4*)(xr + lane * 8);
  float4 v1 = *(const float4*)(xr + lane * 8 + 4);
  float s = v0.x + v0.y + v0.z + v0.w + v1.x + v1.y + v1.z + v1.w;
  float q = v0.x*v0.x + v0.y*v0.y + v0.z*v0.z + v0.w*v0.w
          + v1.x*v1.x + v1.y*v1.y + v1.z*v1.z + v1.w*v1.w;
  for (int m = 1; m <= 32; m <<= 1) {
    s += __shfl_xor(s, m, 64);
    q += __shfl_xor(q, m, 64);
  }
  if (lane == 0) {
    float mean = s * (1.f / 512.f);
    float var = q * (1.f / 512.f) - mean * mean;
    mu[row] = mean;
    rstd[row] = rsqrtf(var + 1e-5f);
  }
}

// ---------------- init hidden state: bf16 linear padded, BOTH parities -------
__global__ void init_h(const float* __restrict__ h0,
                       ushort_t* hi, ushort_t* hc, ushort_t* hm) {
  int i = blockIdx.x * 256 + threadIdx.x;
  if (i >= 64 * 1056) return;
  int b = i / 1056, c = i % 1056;
  if (c < 320) {
    ushort_t v = (c < 308) ? f2bf(h0[b * 1024 + c]) : 0;
    st2(hi + b * 320 + c, v); st2(hi + HI_P + b * 320 + c, v);
  } else if (c < 544) {
    int col = c - 320;
    ushort_t v = (col < 204) ? f2bf(h0[b * 1024 + 308 + col]) : 0;
    st2(hc + b * 224 + col, v); st2(hc + HC_P + b * 224 + col, v);
  } else {
    int col = c - 544;
    ushort_t v = f2bf(h0[b * 1024 + 512 + col]);
    st2(hm + b * 512 + col, v); st2(hm + HM_P + b * 512 + col, v);
  }
}

// ---------------- pack masked weights to bf16 MFMA B-frag order ----------------
struct PackP {
  const float* w[12];
  const float* msk[3];
  ushort_t* pack;
};

__global__ __launch_bounds__(256) void ncp_pack(PackP P) {
  int u = blockIdx.x * 256 + threadIdx.x;
  int layer, rem, KB, K, H, s0p, s0l, s1l;
  size_t base;
  if (u < 133120)      { layer = 0; rem = u;          KB = 26; K = 820; H = 308; s0p = 512; s0l = 512; s1l = 308; base = PACK0; }
  else if (u < 189696) { layer = 1; rem = u - 133120; KB = 17; K = 512; H = 204; s0p = 320; s0l = 308; s1l = 204; base = PACK1; }
  else if (u < 378112) { layer = 2; rem = u - 189696; KB = 23; K = 716; H = 512; s0p = 224; s0l = 204; s1l = 512; base = PACK2; }
  else return;
  const int lane = rem & 63;
  const int mat = (rem >> 6) & 3;
  const int kb = (rem >> 8) % KB;
  const int nt = (rem >> 8) / KB;
  const float* W = P.w[layer * 4 + mat];
  const float* M = (mat < 2) ? P.msk[layer] : nullptr;
  const int n = nt * 16 + (lane & 15);
  const int kbase = kb * 32 + ((lane >> 4) << 3);
  ushort_t* dst = P.pack + base + (size_t)rem * 8;
#pragma unroll
  for (int j = 0; j < 8; ++j) {
    const int kp = kbase + j;
    int ko;
    if (kp < s0p) ko = (kp < s0l) ? kp : -1;
    else { const int ks = kp - s0p; ko = (ks < s1l) ? (s0l + ks) : -1; }
    float v = 0.f;
    if (n < H && ko >= 0) {
      v = W[(size_t)n * K + ko];
      if (M) v *= M[(size_t)n * K + ko];
    }
    dst[j] = f2bf(v);
  }
}

// ---------------- main persistent kernel ----------------
struct MainP {
  const float* x;
  const float* gamma;
  const float* beta;
  const float* bias[12];
  const float* mu;
  const float* rstd;
  ushort_t* hi;
  ushort_t* hc;
  ushort_t* hm;
  const ushort_t* pack;
  unsigned* bar;
  float* y;
  float* hfin;
};

// depth-4 software-pipelined MFMA span over one LDS region
template<int KBT>
__device__ __forceinline__ void mfma_span(const ushort_t* __restrict__ bp,
                                          const ushort_t* __restrict__ lds, int lane,
                                          f32x4& a0, f32x4& a1, f32x4& a2, f32x4& a3) {
  const ushort_t* bb = bp + lane * 8;
  short8 buf[4][4];
#pragma unroll
  for (int kb = 0; kb < 4 && kb < KBT; ++kb) {
    const ushort_t* q = bb + (size_t)kb * 2048;
    buf[kb][0] = *(const short8*)(q);
    buf[kb][1] = *(const short8*)(q + 512);
    buf[kb][2] = *(const short8*)(q + 1024);
    buf[kb][3] = *(const short8*)(q + 1536);
  }
#pragma unroll
  for (int kb = 0; kb < KBT; ++kb) {
    short8 av = *(const short8*)(lds + (size_t)(kb * 64 + lane) * 8);
    a0 = __builtin_amdgcn_mfma_f32_16x16x32_bf16(av, buf[kb & 3][0], a0, 0, 0, 0);
    a1 = __builtin_amdgcn_mfma_f32_16x16x32_bf16(av, buf[kb & 3][1], a1, 0, 0, 0);
    a2 = __builtin_amdgcn_mfma_f32_16x16x32_bf16(av, buf[kb & 3][2], a2, 0, 0, 0);
    a3 = __builtin_amdgcn_mfma_f32_16x16x32_bf16(av, buf[kb & 3][3], a3, 0, 0, 0);
    if (kb + 4 < KBT) {
      const ushort_t* q = bb + (size_t)(kb + 4) * 2048;
      buf[kb & 3][0] = *(const short8*)(q);
      buf[kb & 3][1] = *(const short8*)(q + 512);
      buf[kb & 3][2] = *(const short8*)(q + 1024);
      buf[kb & 3][3] = *(const short8*)(q + 1536);
    }
  }
}

template<int KB1, int KB2, int H, int STP>
__device__ __forceinline__ void tile_phase(
    const ushort_t* __restrict__ packL,
    const ushort_t* __restrict__ lds1, const ushort_t* __restrict__ lds2,
    int nt, int lane, int mtile, int t, bool last,
    const float* __restrict__ bp1, const float* __restrict__ bp2,
    const float* __restrict__ bpa, const float* __restrict__ bpb,
    ushort_t* __restrict__ hout, float* __restrict__ y,
    float* __restrict__ hfin, int hoff)
{
  f32x4 a0 = {0.f, 0.f, 0.f, 0.f}, a1 = a0, a2 = a0, a3 = a0;
  const ushort_t* bp = packL + (size_t)nt * (KB1 + KB2) * 2048;
  mfma_span<KB1>(bp, lds1, lane, a0, a1, a2, a3);
  mfma_span<KB2>(bp + KB1 * 2048, lds2, lane, a0, a1, a2, a3);
  const int n = nt * 16 + (lane & 15);
  if (n < H) {
    float c1 = bp1[n], c2 = bp2[n], ca = bpa[n], cb = bpb[n];
    const int r0 = (lane >> 4) << 2;
#pragma unroll
    for (int j = 0; j < 4; ++j) {
      int brow = mtile * 16 + r0 + j;
      float s = 1.f / (1.f + __expf(-(a2[j] + ca + a3[j] + cb)));
      float f1 = 1.f - 2.f / (1.f + __expf(2.f * (a0[j] + c1)));
      float f2 = 1.f - 2.f / (1.f + __expf(2.f * (a1[j] + c2)));
      float v = f1 * (1.f - s) + s * f2;
      st2(hout + (size_t)brow * STP + n, f2bf(v));
      if (y) y[((size_t)brow * T_STEPS + t) * 512 + n] = v;
      if (last) hfin[brow * 1024 + hoff + n] = v;
    }
  }
}

// stage up to two bf16 padded segments; coalesced 8B units, all loads issued
// before any LDS write -> ~1 coherent-point round trip.
template<int S1, int ST1, int S2, int ST2>
__device__ __forceinline__ void stage2(ushort_t* __restrict__ r1, const ushort_t* __restrict__ h1,
                                       ushort_t* __restrict__ r2, const ushort_t* __restrict__ h2,
                                       int tid) {
  constexpr int U1 = S1 * 2, U2 = S2 * 2;
  constexpr int I1 = (U1 + 255) / 256;
  constexpr int I2 = (U2 + 255) / 256;
  u64_t a[I1];
  u64_t b[I2 > 0 ? I2 : 1];
#pragma unroll
  for (int i = 0; i < I1; ++i) {
    const int u = tid + i * 256;
    if ((U1 & 255) == 0 || u < U1) {
      const int slot = u >> 1;
      a[i] = ld8(h1 + (slot & 15) * ST1 + (slot >> 6) * 32 + ((slot >> 4) & 3) * 8 + (u & 1) * 4);
    }
  }
  if constexpr (S2 > 0) {
#pragma unroll
    for (int i = 0; i < I2; ++i) {
      const int u = tid + i * 256;
      if ((U2 & 255) == 0 || u < U2) {
        const int slot = u >> 1;
        b[i] = ld8(h2 + (slot & 15) * ST2 + (slot >> 6) * 32 + ((slot >> 4) & 3) * 8 + (u & 1) * 4);
      }
    }
  }
#pragma unroll
  for (int i = 0; i < I1; ++i) {
    const int u = tid + i * 256;
    if ((U1 & 255) == 0 || u < U1) *(u64_t*)(r1 + (size_t)u * 4) = a[i];
  }
  if constexpr (S2 > 0) {
#pragma unroll
    for (int i = 0; i < I2; ++i) {
      const int u = tid + i * 256;
      if ((U2 & 255) == 0 || u < U2) *(u64_t*)(r2 + (size_t)u * 4) = b[i];
    }
  }
}

__device__ __forceinline__ void stage_xn(ushort_t* __restrict__ XN, const MainP& P,
                                         int mtile, int tid, int t) {
#pragma unroll
  for (int i = 0; i < 4; ++i) {
    const int s = tid + i * 256;
    const int ln = s & 63;
    const int brow = mtile * 16 + (ln & 15);
    const int kbase = (s >> 6) * 32 + ((ln >> 4) << 3);
    const float muv = P.mu[brow * T_STEPS + t];
    const float rsv = P.rstd[brow * T_STEPS + t];
    const float* xrow = P.x + ((size_t)brow * T_STEPS + t) * 512;
    short8 w;
#pragma unroll
    for (int j = 0; j < 8; ++j)
      w[j] = f2bf((xrow[kbase + j] - muv) * rsv * P.gamma[kbase + j] + P.beta[kbase + j]);
    *(short8*)(XN + (size_t)s * 8) = w;
  }
}

__global__ __launch_bounds__(256) void ncp_main(MainP P) {
  const int tid = threadIdx.x;
  const int lane = tid & 63;
  const int wv = tid >> 6;
  const int wg = blockIdx.x;
  const int mt = wg / 17;        // 0..3 (16 batch rows each; mtiles fully independent)
  const int r  = wg % 17;        // 0..4: L0, 5..8: L1, 9..16: L2

  __shared__ __align__(16) ushort_t Alds[2688 * 8];  // 42 KB max (L0 layout)
  // L0: XN parity0 [0..1023], XN parity1 [1024..2047], HI [2048..2687]
  // L1: HI [0..639], HC [640..1087]
  // L2: HC [0..447], HM [448..1471]

  // ---- dataflow-flag setup ----
  unsigned* wf = P.bar + mt * 64;        // wflag[0..16]
  unsigned* rf = wf + 32;                // rflag[0..16]
  int wa, wb, ra, rb;
  if (r < 5)      { wa = 0; wb = 5;  ra = 0; rb = 9;  }
  else if (r < 9) { wa = 0; wb = 9;  ra = 5; rb = 17; }
  else            { wa = 5; wb = 17; ra = 9; rb = 17; }
  const int nw = wb - wa, nr = rb - ra;
  const unsigned* paddr = wf;            // safe default for inactive lanes
  bool act = false;
  if (lane < nw)           { paddr = wf + wa + lane;        act = true; }
  else if (lane < nw + nr) { paddr = rf + ra + (lane - nw); act = true; }

  if (r < 5) stage_xn(Alds, P, mt, tid, 0);  // prologue XN(0) into parity-0

  for (int s = 0; s < T_STEPS + 2; ++s) {
    // ---- wait: producers' wflags and my-buffer-readers' rflags >= s ----
    if (wv == 0) {
      const unsigned need = (unsigned)s;
      for (;;) {
        unsigned v = act ? ldf(paddr) : 0xFFFFFFFFu;
        if (__all((int)(v >= need))) break;
      }
    }
    __syncthreads();   // release (also orders prev-slot XN prefetch LDS writes)

    // ---- stage ----
    if (r < 5) {
      if (s < T_STEPS)
        stage2<640, 320, 0, 0>(Alds + 2048 * 8,
                               P.hi + (((s - 1) & 1) * 64 + mt * 16) * 320,
                               nullptr, nullptr, tid);
    } else if (r < 9) {
      if (s >= 1 && s <= T_STEPS) {
        const int u = s - 1;
        stage2<640, 320, 448, 224>(Alds, P.hi + ((u & 1) * 64 + mt * 16) * 320,
                                   Alds + 640 * 8,
                                   P.hc + (((u - 1) & 1) * 64 + mt * 16) * 224, tid);
      }
    } else {
      if (s >= 2) {
        const int w = s - 2;
        stage2<448, 224, 1024, 512>(Alds, P.hc + ((w & 1) * 64 + mt * 16) * 224,
                                    Alds + 448 * 8,
                                    P.hm + (((w - 1) & 1) * 64 + mt * 16) * 512, tid);
      }
    }
    __syncthreads();                      // (A) staging consumed, LDS ready
    if (tid == 0) stf(rf + r, (unsigned)(s + 1));

    // ---- compute ----
    if (r < 5) {
      if (s < T_STEPS)
        tile_phase<16, 10, 308, 320>(P.pack + PACK0, Alds + (s & 1) * (1024 * 8),
                                     Alds + 2048 * 8, r * 4 + wv, lane, mt, s,
                                     s == T_STEPS - 1,
                                     P.bias[0], P.bias[1], P.bias[2], P.bias[3],
                                     P.hi + (s & 1) * HI_P, nullptr, P.hfin, 0);
    } else if (r < 9) {
      if (s >= 1 && s <= T_STEPS) {
        const int u = s - 1, nt = (r - 5) * 4 + wv;
        if (nt < 13)
          tile_phase<10, 7, 204, 224>(P.pack + PACK1, Alds, Alds + 640 * 8,
                                      nt, lane, mt, u, u == T_STEPS - 1,
                                      P.bias[4], P.bias[5], P.bias[6], P.bias[7],
                                      P.hc + (u & 1) * HC_P, nullptr, P.hfin, 308);
      }
    } else {
      if (s >= 2) {
        const int w = s - 2;
        tile_phase<7, 16, 512, 512>(P.pack + PACK2, Alds, Alds + 448 * 8,
                                    (r - 9) * 4 + wv, lane, mt, w, w == T_STEPS - 1,
                                    P.bias[8], P.bias[9], P.bias[10], P.bias[11],
                                    P.hm + (w & 1) * HM_P, P.y, P.hfin, 512);
      }
    }
    asm volatile("s_waitcnt vmcnt(0)" ::: "memory");  // per-wave store drain
    __syncthreads();                      // (B) ALL waves' h stores at coherent pt
    if (tid == 0) stf(wf + r, (unsigned)(s + 1));

    // ---- off critical path: L0 prefetches XN(s+1) into other parity ----
    if (r < 5 && s + 1 < T_STEPS)
      stage_xn(Alds + ((s + 1) & 1) * (1024 * 8), P, mt, tid, s + 1);
  }
}

extern "C" void kernel_launch(void* const* d_in, const int* in_sizes, int n_in,
                              void* d_out, int out_size, void* d_ws, size_t ws_size,
                              hipStream_t stream) {
  const float* x     = (const float*)d_in[27];
  const float* h0    = (const float*)d_in[28];
  const float* gamma = (const float*)d_in[29];
  const float* beta  = (const float*)d_in[30];

  char* ws = (char*)d_ws;
  unsigned* bar = (unsigned*)(ws + WS_BAR);
  float* mu   = (float*)(ws + WS_MU);
  float* rstd = (float*)(ws + WS_RSTD);
  ushort_t* hi = (ushort_t*)(ws + WS_HI);
  ushort_t* hc = (ushort_t*)(ws + WS_HC);
  ushort_t* hm = (ushort_t*)(ws + WS_HM);
  ushort_t* pack = (ushort_t*)(ws + WS_PACK);

  float* y = (float*)d_out;
  float* hfin = y + (size_t)64 * 1024 * 512;

  hipMemsetAsync(bar, 0, 4096, stream);

  ln_stats<<<dim3(16384), dim3(256), 0, stream>>>(x, mu, rstd);
  init_h<<<dim3(264), dim3(256), 0, stream>>>(h0, hi, hc, hm);

  PackP pp;
  for (int l = 0; l < 3; ++l) {
    for (int m = 0; m < 4; ++m) pp.w[l * 4 + m] = (const float*)d_in[l * 9 + 2 * m];
    pp.msk[l] = (const float*)d_in[l * 9 + 8];
  }
  pp.pack = pack;
  ncp_pack<<<dim3(1477), dim3(256), 0, stream>>>(pp);

  MainP mp;
  mp.x = x; mp.gamma = gamma; mp.beta = beta;
  for (int l = 0; l < 3; ++l)
    for (int m = 0; m < 4; ++m) mp.bias[l * 4 + m] = (const float*)d_in[l * 9 + 2 * m + 1];
  mp.mu = mu; mp.rstd = rstd;
  mp.hi = hi; mp.hc = hc; mp.hm = hm;
  mp.pack = pack; mp.bar = bar;
  mp.y = y; mp.hfin = hfin;
  ncp_main<<<dim3(NWG), dim3(256), 0, stream>>>(mp);
}

// Round 9
// 11456.184 us; speedup vs baseline: 5.2598x; 1.8087x over previous
//
#include <hip/hip_runtime.h>

typedef __attribute__((ext_vector_type(8))) short short8;
typedef __attribute__((ext_vector_type(4))) float f32x4;
typedef unsigned short ushort_t;
typedef unsigned long long u64_t;

#define T_STEPS 1024
#define NWG 132
#define NWG_MT 33

// Padded-segment geometry:
//   XN 512 (16 kb) | HI 308->320 (10 kb) | HC 204->224 (7 kb) | HM 512 (16 kb)
// L0: A = XN ++ HI  KB=26 (16+10)  NT=20  (10 WGs/mtile, r=0..9)
// L1: A = HI ++ HC  KB=17 (10+7)   NT=13  (7 WGs/mtile,  r=10..16)
// L2: A = HC ++ HM  KB=23 (7+16)   NT=32  (16 WGs/mtile, r=17..32)
// Each WG owns 2 tiles; each tile computed by a WAVE PAIR: lo wave = seg1
// span, hi wave = seg2 span, accumulated through LDS. Halves per-CU B-bytes
// and per-wave serial kb-chain vs round 8 (sync protocol unchanged).
// Pipeline slot s: L0 step s, L1 step s-1, L2 step s-2; dataflow flags.

#define PACK0 0
#define PACK1 1064960            // 20*26*2048
#define PACK2 1517568            // PACK1 + 13*17*2048

#define HI_P (64*320)
#define HC_P (64*224)
#define HM_P (64*512)

// ws offsets (bytes)
#define WS_BAR   0
#define WS_MU    4096
#define WS_RSTD  266240
#define WS_HI    528384
#define WS_HC    610304
#define WS_HM    667648
#define WS_PACK  798720

__device__ __forceinline__ ushort_t f2bf(float f) {
  union { float f; unsigned u; } un; un.f = f;
  unsigned r = (un.u + 0x7fffu + ((un.u >> 16) & 1u)) >> 16;
  return (ushort_t)r;
}

__device__ __forceinline__ void st2(ushort_t* p, ushort_t v) {
  __hip_atomic_store(p, v, __ATOMIC_RELAXED, __HIP_MEMORY_SCOPE_SYSTEM);
}
__device__ __forceinline__ u64_t ld8(const ushort_t* p) {
  return __hip_atomic_load((const u64_t*)p, __ATOMIC_RELAXED, __HIP_MEMORY_SCOPE_SYSTEM);
}
__device__ __forceinline__ unsigned ldf(const unsigned* p) {
  return __hip_atomic_load(p, __ATOMIC_RELAXED, __HIP_MEMORY_SCOPE_SYSTEM);
}
__device__ __forceinline__ void stf(unsigned* p, unsigned v) {
  __hip_atomic_store(p, v, __ATOMIC_RELAXED, __HIP_MEMORY_SCOPE_SYSTEM);
}

// ---------------- LayerNorm stats ----------------
__global__ __launch_bounds__(256) void ln_stats(const float* __restrict__ x,
                                                float* __restrict__ mu,
                                                float* __restrict__ rstd) {
  const int row = blockIdx.x * 4 + (threadIdx.x >> 6);
  const int lane = threadIdx.x & 63;
  const float* xr = x + (size_t)row * 512;
  float4 v0 = *(const float4*)(xr + lane * 8);
  float4 v1 = *(const float4*)(xr + lane * 8 + 4);
  float s = v0.x + v0.y + v0.z + v0.w + v1.x + v1.y + v1.z + v1.w;
  float q = v0.x*v0.x + v0.y*v0.y + v0.z*v0.z + v0.w*v0.w
          + v1.x*v1.x + v1.y*v1.y + v1.z*v1.z + v1.w*v1.w;
  for (int m = 1; m <= 32; m <<= 1) {
    s += __shfl_xor(s, m, 64);
    q += __shfl_xor(q, m, 64);
  }
  if (lane == 0) {
    float mean = s * (1.f / 512.f);
    float var = q * (1.f / 512.f) - mean * mean;
    mu[row] = mean;
    rstd[row] = rsqrtf(var + 1e-5f);
  }
}

// ---------------- init hidden state: bf16 linear padded, BOTH parities -------
__global__ void init_h(const float* __restrict__ h0,
                       ushort_t* hi, ushort_t* hc, ushort_t* hm) {
  int i = blockIdx.x * 256 + threadIdx.x;
  if (i >= 64 * 1056) return;
  int b = i / 1056, c = i % 1056;
  if (c < 320) {
    ushort_t v = (c < 308) ? f2bf(h0[b * 1024 + c]) : 0;
    st2(hi + b * 320 + c, v); st2(hi + HI_P + b * 320 + c, v);
  } else if (c < 544) {
    int col = c - 320;
    ushort_t v = (col < 204) ? f2bf(h0[b * 1024 + 308 + col]) : 0;
    st2(hc + b * 224 + col, v); st2(hc + HC_P + b * 224 + col, v);
  } else {
    int col = c - 544;
    ushort_t v = f2bf(h0[b * 1024 + 512 + col]);
    st2(hm + b * 512 + col, v); st2(hm + HM_P + b * 512 + col, v);
  }
}

// ---------------- pack masked weights ----------------
struct PackP {
  const float* w[12];
  const float* msk[3];
  ushort_t* pack;
};

__global__ __launch_bounds__(256) void ncp_pack(PackP P) {
  int u = blockIdx.x * 256 + threadIdx.x;
  int layer, rem, KB, K, H, s0p, s0l, s1l;
  size_t base;
  if (u < 133120)      { layer = 0; rem = u;          KB = 26; K = 820; H = 308; s0p = 512; s0l = 512; s1l = 308; base = PACK0; }
  else if (u < 189696) { layer = 1; rem = u - 133120; KB = 17; K = 512; H = 204; s0p = 320; s0l = 308; s1l = 204; base = PACK1; }
  else if (u < 378112) { layer = 2; rem = u - 189696; KB = 23; K = 716; H = 512; s0p = 224; s0l = 204; s1l = 512; base = PACK2; }
  else return;
  const int lane = rem & 63;
  const int mat = (rem >> 6) & 3;
  const int kb = (rem >> 8) % KB;
  const int nt = (rem >> 8) / KB;
  const float* W = P.w[layer * 4 + mat];
  const float* M = (mat < 2) ? P.msk[layer] : nullptr;
  const int n = nt * 16 + (lane & 15);
  const int kbase = kb * 32 + ((lane >> 4) << 3);
  ushort_t* dst = P.pack + base + (size_t)rem * 8;
#pragma unroll
  for (int j = 0; j < 8; ++j) {
    const int kp = kbase + j;
    int ko;
    if (kp < s0p) ko = (kp < s0l) ? kp : -1;
    else { const int ks = kp - s0p; ko = (ks < s1l) ? (s0l + ks) : -1; }
    float v = 0.f;
    if (n < H && ko >= 0) {
      v = W[(size_t)n * K + ko];
      if (M) v *= M[(size_t)n * K + ko];
    }
    dst[j] = f2bf(v);
  }
}

// ---------------- main persistent kernel ----------------
struct MainP {
  const float* x;
  const float* gamma;
  const float* beta;
  const float* bias[12];
  const float* mu;
  const float* rstd;
  ushort_t* hi;
  ushort_t* hc;
  ushort_t* hm;
  const ushort_t* pack;
  unsigned* bar;
  float* y;
  float* hfin;
};

// depth-4 software-pipelined MFMA span over one LDS region
template<int KBT>
__device__ __forceinline__ void mfma_span(const ushort_t* __restrict__ bp,
                                          const ushort_t* __restrict__ lds, int lane,
                                          f32x4& a0, f32x4& a1, f32x4& a2, f32x4& a3) {
  const ushort_t* bb = bp + lane * 8;
  short8 buf[4][4];
#pragma unroll
  for (int kb = 0; kb < 4 && kb < KBT; ++kb) {
    const ushort_t* q = bb + (size_t)kb * 2048;
    buf[kb][0] = *(const short8*)(q);
    buf[kb][1] = *(const short8*)(q + 512);
    buf[kb][2] = *(const short8*)(q + 1024);
    buf[kb][3] = *(const short8*)(q + 1536);
  }
#pragma unroll
  for (int kb = 0; kb < KBT; ++kb) {
    short8 av = *(const short8*)(lds + (size_t)(kb * 64 + lane) * 8);
    a0 = __builtin_amdgcn_mfma_f32_16x16x32_bf16(av, buf[kb & 3][0], a0, 0, 0, 0);
    a1 = __builtin_amdgcn_mfma_f32_16x16x32_bf16(av, buf[kb & 3][1], a1, 0, 0, 0);
    a2 = __builtin_amdgcn_mfma_f32_16x16x32_bf16(av, buf[kb & 3][2], a2, 0, 0, 0);
    a3 = __builtin_amdgcn_mfma_f32_16x16x32_bf16(av, buf[kb & 3][3], a3, 0, 0, 0);
    if (kb + 4 < KBT) {
      const ushort_t* q = bb + (size_t)(kb + 4) * 2048;
      buf[kb & 3][0] = *(const short8*)(q);
      buf[kb & 3][1] = *(const short8*)(q + 512);
      buf[kb & 3][2] = *(const short8*)(q + 1024);
      buf[kb & 3][3] = *(const short8*)(q + 1536);
    }
  }
}

// epilogue by the lo wave after pair accumulation
template<int H, int STP>
__device__ __forceinline__ void epilogue(const f32x4* A, int nt, int lane, int mtile,
                                         int t, bool last,
                                         const float* __restrict__ bp1, const float* __restrict__ bp2,
                                         const float* __restrict__ bpa, const float* __restrict__ bpb,
                                         ushort_t* __restrict__ hout, float* __restrict__ y,
                                         float* __restrict__ hfin, int hoff) {
  const int n = nt * 16 + (lane & 15);
  if (n < H) {
    float c1 = bp1[n], c2 = bp2[n], ca = bpa[n], cb = bpb[n];
    const int r0 = (lane >> 4) << 2;
#pragma unroll
    for (int j = 0; j < 4; ++j) {
      int brow = mtile * 16 + r0 + j;
      float s = 1.f / (1.f + __expf(-(A[2][j] + ca + A[3][j] + cb)));
      float f1 = 1.f - 2.f / (1.f + __expf(2.f * (A[0][j] + c1)));
      float f2 = 1.f - 2.f / (1.f + __expf(2.f * (A[1][j] + c2)));
      float v = f1 * (1.f - s) + s * f2;
      st2(hout + (size_t)brow * STP + n, f2bf(v));
      if (y) y[((size_t)brow * T_STEPS + t) * 512 + n] = v;
      if (last) hfin[brow * 1024 + hoff + n] = v;
    }
  }
}

// stage up to two bf16 padded segments; coalesced 8B units, all loads issued
// before any LDS write -> ~1 coherent-point round trip.
template<int S1, int ST1, int S2, int ST2>
__device__ __forceinline__ void stage2(ushort_t* __restrict__ r1, const ushort_t* __restrict__ h1,
                                       ushort_t* __restrict__ r2, const ushort_t* __restrict__ h2,
                                       int tid) {
  constexpr int U1 = S1 * 2, U2 = S2 * 2;
  constexpr int I1 = (U1 + 255) / 256;
  constexpr int I2 = (U2 + 255) / 256;
  u64_t a[I1];
  u64_t b[I2 > 0 ? I2 : 1];
#pragma unroll
  for (int i = 0; i < I1; ++i) {
    const int u = tid + i * 256;
    if ((U1 & 255) == 0 || u < U1) {
      const int slot = u >> 1;
      a[i] = ld8(h1 + (slot & 15) * ST1 + (slot >> 6) * 32 + ((slot >> 4) & 3) * 8 + (u & 1) * 4);
    }
  }
  if constexpr (S2 > 0) {
#pragma unroll
    for (int i = 0; i < I2; ++i) {
      const int u = tid + i * 256;
      if ((U2 & 255) == 0 || u < U2) {
        const int slot = u >> 1;
        b[i] = ld8(h2 + (slot & 15) * ST2 + (slot >> 6) * 32 + ((slot >> 4) & 3) * 8 + (u & 1) * 4);
      }
    }
  }
#pragma unroll
  for (int i = 0; i < I1; ++i) {
    const int u = tid + i * 256;
    if ((U1 & 255) == 0 || u < U1) *(u64_t*)(r1 + (size_t)u * 4) = a[i];
  }
  if constexpr (S2 > 0) {
#pragma unroll
    for (int i = 0; i < I2; ++i) {
      const int u = tid + i * 256;
      if ((U2 & 255) == 0 || u < U2) *(u64_t*)(r2 + (size_t)u * 4) = b[i];
    }
  }
}

__device__ __forceinline__ void stage_xn(ushort_t* __restrict__ XN, const MainP& P,
                                         int mtile, int tid, int t) {
#pragma unroll
  for (int i = 0; i < 4; ++i) {
    const int s = tid + i * 256;
    const int ln = s & 63;
    const int brow = mtile * 16 + (ln & 15);
    const int kbase = (s >> 6) * 32 + ((ln >> 4) << 3);
    const float muv = P.mu[brow * T_STEPS + t];
    const float rsv = P.rstd[brow * T_STEPS + t];
    const float* xrow = P.x + ((size_t)brow * T_STEPS + t) * 512;
    short8 w;
#pragma unroll
    for (int j = 0; j < 8; ++j)
      w[j] = f2bf((xrow[kbase + j] - muv) * rsv * P.gamma[kbase + j] + P.beta[kbase + j]);
    *(short8*)(XN + (size_t)s * 8) = w;
  }
}

__global__ __launch_bounds__(256) void ncp_main(MainP P) {
  const int tid = threadIdx.x;
  const int lane = tid & 63;
  const int wv = tid >> 6;
  const int role = wv & 1;        // 0 = seg1 span + epilogue, 1 = seg2 span
  const int tslot = wv >> 1;      // which of the WG's 2 tiles
  const int wg = blockIdx.x;
  const int mt = wg / NWG_MT;     // 0..3
  const int r  = wg % NWG_MT;     // 0..9: L0, 10..16: L1, 17..32: L2

  __shared__ __align__(16) ushort_t Alds[2688 * 8];  // 42 KB staging (L0 layout)
  __shared__ __align__(16) f32x4 accum[2][64][4];    // 8 KB pair-accumulate
  // L0: XN parity0 [0..1023], XN parity1 [1024..2047], HI [2048..2687]
  // L1: HI [0..639], HC [640..1087]
  // L2: HC [0..447], HM [448..1471]

  // ---- dataflow-flag setup (same protocol as round 8, 33 WGs/mtile) ----
  unsigned* wf = P.bar + mt * 128;       // wflag[0..32]
  unsigned* rf = wf + 64;                // rflag[0..32]
  int wa, wb, ra, rb;
  if (r < 10)      { wa = 0;  wb = 10; ra = 0;  rb = 17; }
  else if (r < 17) { wa = 0;  wb = 17; ra = 10; rb = 33; }
  else             { wa = 10; wb = 33; ra = 17; rb = 33; }
  const int nw = wb - wa, nr = rb - ra;
  const unsigned* paddr = wf;
  bool pact = false;
  if (lane < nw)           { paddr = wf + wa + lane;        pact = true; }
  else if (lane < nw + nr) { paddr = rf + ra + (lane - nw); pact = true; }

  if (r < 10) stage_xn(Alds, P, mt, tid, 0);  // prologue XN(0) into parity-0

  for (int s = 0; s < T_STEPS + 2; ++s) {
    // ---- wait ----
    if (wv == 0) {
      const unsigned need = (unsigned)s;
      for (;;) {
        unsigned v = pact ? ldf(paddr) : 0xFFFFFFFFu;
        if (__all((int)(v >= need))) break;
      }
    }
    __syncthreads();

    // ---- per-layer slot state ----
    int nt = 0, tstep = 0;
    bool on = false;
    if (r < 10)      { nt = r * 2 + tslot;        tstep = s;     on = (s < T_STEPS); }
    else if (r < 17) { nt = (r - 10) * 2 + tslot; tstep = s - 1; on = (s >= 1 && s <= T_STEPS) && (nt < 13); }
    else             { nt = (r - 17) * 2 + tslot; tstep = s - 2; on = (s >= 2); }
    const bool last = (tstep == T_STEPS - 1);

    // ---- stage ----
    if (r < 10) {
      if (s < T_STEPS)
        stage2<640, 320, 0, 0>(Alds + 2048 * 8,
                               P.hi + (((s - 1) & 1) * 64 + mt * 16) * 320,
                               nullptr, nullptr, tid);
    } else if (r < 17) {
      if (s >= 1 && s <= T_STEPS)
        stage2<640, 320, 448, 224>(Alds, P.hi + (((s - 1) & 1) * 64 + mt * 16) * 320,
                                   Alds + 640 * 8,
                                   P.hc + (((s - 2) & 1) * 64 + mt * 16) * 224, tid);
    } else {
      if (s >= 2)
        stage2<448, 224, 1024, 512>(Alds, P.hc + (((s - 2) & 1) * 64 + mt * 16) * 224,
                                    Alds + 448 * 8,
                                    P.hm + (((s - 3) & 1) * 64 + mt * 16) * 512, tid);
    }
    __syncthreads();                      // (A) LDS staged
    if (tid == 0) stf(rf + r, (unsigned)(s + 1));

    // ---- spans (pair-split) ----
    f32x4 A[4];
#pragma unroll
    for (int j = 0; j < 4; ++j) A[j] = {0.f, 0.f, 0.f, 0.f};
    if (on) {
      if (r < 10) {
        const ushort_t* bp = P.pack + PACK0 + (size_t)nt * 26 * 2048;
        if (role == 0) mfma_span<16>(bp, Alds + (s & 1) * (1024 * 8), lane, A[0], A[1], A[2], A[3]);
        else           mfma_span<10>(bp + 16 * 2048, Alds + 2048 * 8, lane, A[0], A[1], A[2], A[3]);
      } else if (r < 17) {
        const ushort_t* bp = P.pack + PACK1 + (size_t)nt * 17 * 2048;
        if (role == 0) mfma_span<10>(bp, Alds, lane, A[0], A[1], A[2], A[3]);
        else           mfma_span<7>(bp + 10 * 2048, Alds + 640 * 8, lane, A[0], A[1], A[2], A[3]);
      } else {
        const ushort_t* bp = P.pack + PACK2 + (size_t)nt * 23 * 2048;
        if (role == 0) mfma_span<7>(bp, Alds, lane, A[0], A[1], A[2], A[3]);
        else           mfma_span<16>(bp + 7 * 2048, Alds + 448 * 8, lane, A[0], A[1], A[2], A[3]);
      }
      if (role == 1) {
#pragma unroll
        for (int j = 0; j < 4; ++j) accum[tslot][lane][j] = A[j];
      }
    }
    __syncthreads();                      // (A2) partner accumulator ready

    // ---- epilogue (lo wave adds partner + activations + stores) ----
    if (on && role == 0) {
#pragma unroll
      for (int j = 0; j < 4; ++j) {
        f32x4 p = accum[tslot][lane][j];
        A[j][0] += p[0]; A[j][1] += p[1]; A[j][2] += p[2]; A[j][3] += p[3];
      }
      if (r < 10)
        epilogue<308, 320>(A, nt, lane, mt, tstep, last,
                           P.bias[0], P.bias[1], P.bias[2], P.bias[3],
                           P.hi + (tstep & 1) * HI_P, nullptr, P.hfin, 0);
      else if (r < 17)
        epilogue<204, 224>(A, nt, lane, mt, tstep, last,
                           P.bias[4], P.bias[5], P.bias[6], P.bias[7],
                           P.hc + (tstep & 1) * HC_P, nullptr, P.hfin, 308);
      else
        epilogue<512, 512>(A, nt, lane, mt, tstep, last,
                           P.bias[8], P.bias[9], P.bias[10], P.bias[11],
                           P.hm + (tstep & 1) * HM_P, P.y, P.hfin, 512);
    }
    asm volatile("s_waitcnt vmcnt(0)" ::: "memory");
    __syncthreads();                      // (B) all h stores at coherent point
    if (tid == 0) stf(wf + r, (unsigned)(s + 1));

    // ---- off critical path: L0 prefetches XN(s+1) into other parity ----
    if (r < 10 && s + 1 < T_STEPS)
      stage_xn(Alds + ((s + 1) & 1) * (1024 * 8), P, mt, tid, s + 1);
  }
}

extern "C" void kernel_launch(void* const* d_in, const int* in_sizes, int n_in,
                              void* d_out, int out_size, void* d_ws, size_t ws_size,
                              hipStream_t stream) {
  const float* x     = (const float*)d_in[27];
  const float* h0    = (const float*)d_in[28];
  const float* gamma = (const float*)d_in[29];
  const float* beta  = (const float*)d_in[30];

  char* ws = (char*)d_ws;
  unsigned* bar = (unsigned*)(ws + WS_BAR);
  float* mu   = (float*)(ws + WS_MU);
  float* rstd = (float*)(ws + WS_RSTD);
  ushort_t* hi = (ushort_t*)(ws + WS_HI);
  ushort_t* hc = (ushort_t*)(ws + WS_HC);
  ushort_t* hm = (ushort_t*)(ws + WS_HM);
  ushort_t* pack = (ushort_t*)(ws + WS_PACK);

  float* y = (float*)d_out;
  float* hfin = y + (size_t)64 * 1024 * 512;

  hipMemsetAsync(bar, 0, 4096, stream);

  ln_stats<<<dim3(16384), dim3(256), 0, stream>>>(x, mu, rstd);
  init_h<<<dim3(264), dim3(256), 0, stream>>>(h0, hi, hc, hm);

  PackP pp;
  for (int l = 0; l < 3; ++l) {
    for (int m = 0; m < 4; ++m) pp.w[l * 4 + m] = (const float*)d_in[l * 9 + 2 * m];
    pp.msk[l] = (const float*)d_in[l * 9 + 8];
  }
  pp.pack = pack;
  ncp_pack<<<dim3(1477), dim3(256), 0, stream>>>(pp);

  MainP mp;
  mp.x = x; mp.gamma = gamma; mp.beta = beta;
  for (int l = 0; l < 3; ++l)
    for (int m = 0; m < 4; ++m) mp.bias[l * 4 + m] = (const float*)d_in[l * 9 + 2 * m + 1];
  mp.mu = mu; mp.rstd = rstd;
  mp.hi = hi; mp.hc = hc; mp.hm = hm;
  mp.pack = pack; mp.bar = bar;
  mp.y = y; mp.hfin = hfin;
  ncp_main<<<dim3(NWG), dim3(256), 0, stream>>>(mp);
}